// Round 6
// baseline (17649.551 us; speedup 1.0000x reference)
//
#include <hip/hip_runtime.h>
#include <hip/hip_cooperative_groups.h>

namespace cg = cooperative_groups;

// ---- problem constants ----
constexpr int kB   = 32;
constexpr int kL   = 12;
constexpr int kN   = 325;
constexpr int kNP  = 328;          // padded node count
constexpr int kPc  = kB * kNP;     // 10496 column stride, channel-major
constexpr int kHID = 64;
constexpr int kDIN = 198;          // 3 * 66
constexpr int kND  = 40;
constexpr int kNN2 = kN * kN;
constexpr float cAW = 0.05f, cBW = 0.95f, cGW = 0.95f, cTA = 3.0f;

constexpr int kG = 1024;           // coop grid blocks (4/CU on 256 CUs)
constexpr int kT = 192;            // threads per block (3 waves)

constexpr int kHopU   = 2304;      // 6 wblk * 6 cgrp * 64 (chain,b)
constexpr int kMlpAV  = 765;       // 656 mlp blocks + 109 zero blocks
constexpr int kMlpBV  = 328;
constexpr int kAdjU   = 4032;      // 6 jblk * 21 iblk * 32 b
constexpr int kBldEV  = 1152;      // 6 wblk * 6 vblk * 32 b
constexpr int kGateU  = 2624;      // 164 ptile * 16 hblk
constexpr int kOutU   = 164;
constexpr int kInitT  = 66 * kPc + 2 * kND * kN;

__device__ __forceinline__ float sigm_f(float x) { return 1.f / (1.f + __expf(-x)); }
__device__ __forceinline__ float tanh_f(float x) { return 1.f - 2.f / (1.f + __expf(2.f * x)); }

struct KParams {
    const float *hist, *fut, *adj0, *adj1, *emb1, *emb2;
    const float *hw1, *hb1, *hw2, *hb2, *hw3, *hb3, *rnw, *rnb, *fcw, *fcb;
    float* out;
    float *xH, *hh1a, *hh1b, *hh2a, *hh2b;
    float *zh1a, *zh1b, *zh2a, *zh2b;
    float *tmp, *ch1a, *ch1b, *ch2a, *ch2b;
    float *nv1, *nv2, *zbuf, *s2g, *e1T, *e2T, *rs, *cs, *adjv, *E0, *E1;
};

union SMem {
    float part[2][16][64];   // mlpA partials, 8 KB
    float tile[64][65];      // buildE transpose tile, 16.6 KB
};

// ---------------------------------------------------------------------------
__device__ __forceinline__ void d_init(const KParams& P, int i) {
    if (i < 66 * kPc) {
        int c = i / kPc, p = i - c * kPc;
        int b = p / kNP, n = p - b * kNP;
        if (n < kN) {
            float v = (c < 2) ? P.hist[((b * kL) * kN + n) * 2 + c] : 0.f;
            P.xH[(size_t)c * kPc + p] = v;
        }
    } else {
        int j = i - 66 * kPc;
        if (j < kND * kN) {
            int d = j / kN, n = j - d * kN;
            P.e1T[j] = P.emb1[n * kND + d];
        } else {
            j -= kND * kN;
            int d = j / kN, n = j - d * kN;
            P.e2T[j] = P.emb2[n * kND + d];
        }
    }
}

// ---------------------------------------------------------------------------
// diffusion hop wave-unit: out[c,b,w] = gamma*sum_v M[v,w]*h[c,b,v] + AW*x[c,b,w]
// u = wblk + 6*(cgrp + 6*zb); 11 channels per wave, full K, barrier-free.
__device__ __forceinline__ void d_hop(int u, int lane,
        const float* __restrict__ Ma, const float* __restrict__ Mb, int mstride,
        const float* __restrict__ hA, const float* __restrict__ hB,
        const float* __restrict__ xS, float* __restrict__ oA, float* __restrict__ oB,
        float gamma) {
    const int wblk = u % 6;
    const int rem = u / 6;
    const int cgrp = rem % 6;
    const int zb = rem / 6;              // 0..63
    const int sel = zb >> 5, b = zb & 31;
    const int w = wblk * 64 + lane;
    const int wcl = (w < kN) ? w : (kN - 1);
    const int c0 = cgrp * 11;
    const float* Mp = (sel ? Mb : Ma) + (size_t)b * mstride + wcl;
    const float* h = (sel ? hB : hA) + b * kNP;
    const float* x = xS + b * kNP;
    float* o = (sel ? oB : oA) + b * kNP;

    float acc[11];
#pragma unroll
    for (int i = 0; i < 11; ++i) acc[i] = 0.f;

    int vc = 0;
    for (; vc + 8 <= kN; vc += 8) {
        float m0 = Mp[(size_t)(vc + 0) * kN], m1 = Mp[(size_t)(vc + 1) * kN];
        float m2 = Mp[(size_t)(vc + 2) * kN], m3 = Mp[(size_t)(vc + 3) * kN];
        float m4 = Mp[(size_t)(vc + 4) * kN], m5 = Mp[(size_t)(vc + 5) * kN];
        float m6 = Mp[(size_t)(vc + 6) * kN], m7 = Mp[(size_t)(vc + 7) * kN];
#pragma unroll
        for (int i = 0; i < 11; ++i) {
            const float* hr = h + (size_t)(c0 + i) * kPc + vc;
            float4 A0 = *(const float4*)(hr);
            float4 A1 = *(const float4*)(hr + 4);
            float s = acc[i];
            s = fmaf(m0, A0.x, s); s = fmaf(m1, A0.y, s);
            s = fmaf(m2, A0.z, s); s = fmaf(m3, A0.w, s);
            s = fmaf(m4, A1.x, s); s = fmaf(m5, A1.y, s);
            s = fmaf(m6, A1.z, s); s = fmaf(m7, A1.w, s);
            acc[i] = s;
        }
    }
    for (; vc < kN; ++vc) {
        float m = Mp[(size_t)vc * kN];
#pragma unroll
        for (int i = 0; i < 11; ++i)
            acc[i] = fmaf(m, h[(size_t)(c0 + i) * kPc + vc], acc[i]);
    }
    if (w < kN) {
#pragma unroll
        for (int i = 0; i < 11; ++i) {
            size_t idx = (size_t)(c0 + i) * kPc + w;
            o[idx] = gamma * acc[i] + cAW * x[idx];
        }
    }
}

// ---------------------------------------------------------------------------
// mlpA virtual block: fc1 (198->16, K-split over 3 waves) + fc2 (16->2) -> s2g
// vb in [0,656): (ptile, m).  vb in [656, 765): zero rs/cs.
__device__ __forceinline__ void d_mlpA(SMem& sm, const KParams& P, int hy0, int vb) {
    if (vb >= 656) {
        int z = (vb - 656) * kT + threadIdx.x;
        if (z < kB * kN) P.rs[z] = 0.f;
        else if (z < 2 * kB * kN) P.cs[z - kB * kN] = 0.f;
        return;
    }
    const int lane = threadIdx.x & 63;
    const int wv = threadIdx.x >> 6;
    const int pt = vb >> 2, m = vb & 3;
    const int ig = hy0 + m;
    const int p = pt * 64 + lane;
    const float* src = (wv == 0) ? P.xH
                     : (wv == 1) ? ((m & 1) ? P.hh1b : P.hh1a)
                                 : ((m & 1) ? P.hh2b : P.hh2a);
    const float* wp = P.hw1 + (size_t)ig * (kDIN * 16);
    float acc[16];
#pragma unroll
    for (int o = 0; o < 16; ++o) acc[o] = 0.f;
#pragma unroll 2
    for (int kl = 0; kl < 66; ++kl) {
        int kk = wv * 66 + kl;
        float u = src[(size_t)kl * kPc + p];
        float4 wa = *(const float4*)(wp + kk * 16);
        float4 wb = *(const float4*)(wp + kk * 16 + 4);
        float4 wc = *(const float4*)(wp + kk * 16 + 8);
        float4 wd = *(const float4*)(wp + kk * 16 + 12);
        acc[0]  = fmaf(u, wa.x, acc[0]);  acc[1]  = fmaf(u, wa.y, acc[1]);
        acc[2]  = fmaf(u, wa.z, acc[2]);  acc[3]  = fmaf(u, wa.w, acc[3]);
        acc[4]  = fmaf(u, wb.x, acc[4]);  acc[5]  = fmaf(u, wb.y, acc[5]);
        acc[6]  = fmaf(u, wb.z, acc[6]);  acc[7]  = fmaf(u, wb.w, acc[7]);
        acc[8]  = fmaf(u, wc.x, acc[8]);  acc[9]  = fmaf(u, wc.y, acc[9]);
        acc[10] = fmaf(u, wc.z, acc[10]); acc[11] = fmaf(u, wc.w, acc[11]);
        acc[12] = fmaf(u, wd.x, acc[12]); acc[13] = fmaf(u, wd.y, acc[13]);
        acc[14] = fmaf(u, wd.z, acc[14]); acc[15] = fmaf(u, wd.w, acc[15]);
    }
    if (wv > 0) {
#pragma unroll
        for (int o = 0; o < 16; ++o) sm.part[wv - 1][o][lane] = acc[o];
    }
    __syncthreads();
    if (wv == 0) {
        float sv[16];
#pragma unroll
        for (int o = 0; o < 16; ++o)
            sv[o] = sigm_f(P.hb1[ig * 16 + o] + acc[o] + sm.part[0][o][lane] + sm.part[1][o][lane]);
#pragma unroll
        for (int j = 0; j < 2; ++j) {
            float t = P.hb2[ig * 2 + j];
#pragma unroll
            for (int o = 0; o < 16; ++o) t = fmaf(sv[o], P.hw2[ig * 32 + o * 2 + j], t);
            P.s2g[(size_t)(m * 2 + j) * kPc + p] = sigm_f(t);
        }
    }
    __syncthreads();   // protect sm.part before any next virtual block reuses it
}

// mlpB virtual block: fc3 (2->40) + combine + nv = tanh(TA*emb*f)
__device__ __forceinline__ void d_mlpB(const KParams& P, int hy0, int vb) {
    const int lane = threadIdx.x & 63;
    const int wv = threadIdx.x >> 6;
    const int sel = vb & 1, pt = vb >> 1;
    const int p = pt * 64 + lane;
    const int b = p / kNP, n = p - b * kNP;
    const int nc = (n < kN) ? n : (kN - 1);
    const bool ok = (n < kN);
    const int i0 = hy0 + sel * 2;
    const int rbase = sel * 4;
    float sa0 = P.s2g[(size_t)(rbase + 0) * kPc + p];
    float sa1 = P.s2g[(size_t)(rbase + 1) * kPc + p];
    float sb0 = P.s2g[(size_t)(rbase + 2) * kPc + p];
    float sb1 = P.s2g[(size_t)(rbase + 3) * kPc + p];
    const float* eT = sel ? P.e2T : P.e1T;
    float* nv = sel ? P.nv2 : P.nv1;
    for (int d = wv; d < kND; d += 3) {
        float f = P.hb3[(i0 + 0) * kND + d] + P.hb3[(i0 + 1) * kND + d]
                + sa0 * P.hw3[(i0 + 0) * 80 + d] + sa1 * P.hw3[(i0 + 0) * 80 + 40 + d]
                + sb0 * P.hw3[(i0 + 1) * 80 + d] + sb1 * P.hw3[(i0 + 1) * 80 + 40 + d];
        float r = tanh_f(cTA * eT[d * kN + nc] * f);
        if (ok) nv[(size_t)d * kPc + p] = r;
    }
}

// ---------------------------------------------------------------------------
// adj wave-unit: adjv[i][j] = relu(tanh(TA*(a_ij - a_ji))) + rs/cs atomics
__device__ __forceinline__ void d_adj(const KParams& P, int u, int lane) {
    const int jblk = u % 6;
    const int rem = u / 6;
    const int iblk = rem % 21;
    const int b = rem / 21;
    const int j = jblk * 64 + lane;
    const bool jok = (j < kN);
    const int jc = jok ? j : (kN - 1);
    const int i0 = iblk * 16;
    const float* p1 = P.nv1 + b * kNP;
    const float* p2 = P.nv2 + b * kNP;
    float aij[16], aji[16];
#pragma unroll
    for (int q = 0; q < 16; ++q) { aij[q] = 0.f; aji[q] = 0.f; }
#pragma unroll 2
    for (int d = 0; d < kND; ++d) {
        const float* r1 = p1 + (size_t)d * kPc;
        const float* r2 = p2 + (size_t)d * kPc;
        float x1j = r1[jc];
        float x2j = r2[jc];
        float4 v1a = *(const float4*)(r1 + i0);
        float4 v1b = *(const float4*)(r1 + i0 + 4);
        float4 v1c = *(const float4*)(r1 + i0 + 8);
        float4 v1d = *(const float4*)(r1 + i0 + 12);
        float4 v2a = *(const float4*)(r2 + i0);
        float4 v2b = *(const float4*)(r2 + i0 + 4);
        float4 v2c = *(const float4*)(r2 + i0 + 8);
        float4 v2d = *(const float4*)(r2 + i0 + 12);
        float w1v[16] = {v1a.x,v1a.y,v1a.z,v1a.w, v1b.x,v1b.y,v1b.z,v1b.w,
                         v1c.x,v1c.y,v1c.z,v1c.w, v1d.x,v1d.y,v1d.z,v1d.w};
        float w2v[16] = {v2a.x,v2a.y,v2a.z,v2a.w, v2b.x,v2b.y,v2b.z,v2b.w,
                         v2c.x,v2c.y,v2c.z,v2c.w, v2d.x,v2d.y,v2d.z,v2d.w};
#pragma unroll
        for (int q = 0; q < 16; ++q) {
            aij[q] = fmaf(w1v[q], x2j, aij[q]);
            aji[q] = fmaf(x1j, w2v[q], aji[q]);
        }
    }
    size_t base = (size_t)b * kNN2;
    float colsum = 0.f;
#pragma unroll
    for (int q = 0; q < 16; ++q) {
        int i = i0 + q;
        float tv = tanh_f(cTA * (aij[q] - aji[q]));
        float av = fmaxf(tv, 0.f);
        bool okk = (i < kN) && jok;
        if (okk) P.adjv[base + (size_t)i * kN + j] = av;
        float rv = okk ? av : 0.f;
        colsum += rv;
        float rsum = rv;
#pragma unroll
        for (int off = 32; off; off >>= 1) rsum += __shfl_down(rsum, off);
        if (lane == 0 && i < kN) atomicAdd(&P.rs[b * kN + i], rsum);
    }
    if (jok) atomicAdd(&P.cs[b * kN + j], colsum);
}

// ---------------------------------------------------------------------------
// buildE virtual block: E0/E1 with tiled transpose
__device__ __forceinline__ void d_buildE(SMem& sm, const KParams& P, int vb) {
    const int lane = threadIdx.x & 63;
    const int wv = threadIdx.x >> 6;
    const int w0 = (vb % 6) * 64;
    const int v0 = ((vb / 6) % 6) * 64;
    const int b = vb / 36;
    const float* av = P.adjv + (size_t)b * kNN2;
    for (int r = wv; r < 64; r += 3) {
        int v = v0 + r, w = w0 + lane;
        sm.tile[r][lane] = (v < kN && w < kN) ? av[(size_t)v * kN + w] : 0.f;
    }
    __syncthreads();
    size_t eb = (size_t)b * kNN2;
    for (int r = wv; r < 64; r += 3) {
        {
            int v = v0 + r, w = w0 + lane;
            if (v < kN && w < kN) {
                float iv = 1.f / (1.f + P.rs[b * kN + v]);
                float e = cBW * sm.tile[r][lane] * iv + cGW * P.adj0[v * kN + w];
                if (v == w) e += cBW * iv;
                P.E0[eb + (size_t)v * kN + w] = e;
            }
        }
        {
            int v = w0 + r, w = v0 + lane;
            if (v < kN && w < kN) {
                float iv = 1.f / (1.f + P.cs[b * kN + v]);
                float e = cBW * sm.tile[lane][r] * iv + cGW * P.adj1[v * kN + w];
                if (v == w) e += cBW * iv;
                P.E1[eb + (size_t)v * kN + w] = e;
            }
        }
    }
    __syncthreads();
}

// ---------------------------------------------------------------------------
// gates wave-unit: z,r + tmp=[x, r*H]
__device__ __forceinline__ void d_gates(const KParams& P, int rb, int u, int lane) {
    const int pt = u % 164, hb = u / 164;
    const int p = pt * 64 + lane;
    const int h0 = hb * 4;
    const float* wz0 = P.rnw + (size_t)(rb + 0) * (kDIN * kHID) + h0;
    const float* wz1 = P.rnw + (size_t)(rb + 1) * (kDIN * kHID) + h0;
    const float* wr0 = P.rnw + (size_t)(rb + 2) * (kDIN * kHID) + h0;
    const float* wr1 = P.rnw + (size_t)(rb + 3) * (kDIN * kHID) + h0;
    float az[4] = {0.f, 0.f, 0.f, 0.f}, ar[4] = {0.f, 0.f, 0.f, 0.f};
    const float* segA[3] = {P.xH, P.zh1a, P.zh2a};
    const float* segB[3] = {P.xH, P.zh1b, P.zh2b};
#pragma unroll
    for (int seg = 0; seg < 3; ++seg) {
        const float* sA = segA[seg];
        const float* sB = segB[seg];
        const size_t wo = (size_t)seg * 66 * kHID;
#pragma unroll 2
        for (int kl = 0; kl < 66; ++kl) {
            float u0 = sA[(size_t)kl * kPc + p];
            float u1 = sB[(size_t)kl * kPc + p];
            float4 z0 = *(const float4*)(wz0 + wo + (size_t)kl * kHID);
            float4 z1 = *(const float4*)(wz1 + wo + (size_t)kl * kHID);
            float4 r0 = *(const float4*)(wr0 + wo + (size_t)kl * kHID);
            float4 r1 = *(const float4*)(wr1 + wo + (size_t)kl * kHID);
            az[0] = fmaf(u0, z0.x, az[0]); az[1] = fmaf(u0, z0.y, az[1]);
            az[2] = fmaf(u0, z0.z, az[2]); az[3] = fmaf(u0, z0.w, az[3]);
            az[0] = fmaf(u1, z1.x, az[0]); az[1] = fmaf(u1, z1.y, az[1]);
            az[2] = fmaf(u1, z1.z, az[2]); az[3] = fmaf(u1, z1.w, az[3]);
            ar[0] = fmaf(u0, r0.x, ar[0]); ar[1] = fmaf(u0, r0.y, ar[1]);
            ar[2] = fmaf(u0, r0.z, ar[2]); ar[3] = fmaf(u0, r0.w, ar[3]);
            ar[0] = fmaf(u1, r1.x, ar[0]); ar[1] = fmaf(u1, r1.y, ar[1]);
            ar[2] = fmaf(u1, r1.z, ar[2]); ar[3] = fmaf(u1, r1.w, ar[3]);
        }
    }
    const int b = p / kNP, n = p - b * kNP;
    const bool ok = (n < kN);
#pragma unroll
    for (int i = 0; i < 4; ++i) {
        float zz = sigm_f(az[i] + P.rnb[(rb + 0) * kHID + h0 + i] + P.rnb[(rb + 1) * kHID + h0 + i]);
        float rr = sigm_f(ar[i] + P.rnb[(rb + 2) * kHID + h0 + i] + P.rnb[(rb + 3) * kHID + h0 + i]);
        float tv = rr * P.xH[(size_t)(2 + h0 + i) * kPc + p];
        if (ok) {
            P.zbuf[(size_t)(h0 + i) * kPc + p] = zz;
            P.tmp[(size_t)(2 + h0 + i) * kPc + p] = tv;
        }
    }
    if (hb == 0 && ok) {
        P.tmp[p] = P.xH[p];
        P.tmp[kPc + p] = P.xH[kPc + p];
    }
}

// ---------------------------------------------------------------------------
// final wave-unit: Cn + GRU update in place + next-step x rows
__device__ __forceinline__ void d_final(const KParams& P, int rb, int t, int nextmode,
                                        int u, int lane) {
    const int pt = u % 164, hb = u / 164;
    const int p = pt * 64 + lane;
    const int h0 = hb * 4;
    const float* wc0 = P.rnw + (size_t)(rb + 4) * (kDIN * kHID) + h0;
    const float* wc1 = P.rnw + (size_t)(rb + 5) * (kDIN * kHID) + h0;
    float ac[4] = {0.f, 0.f, 0.f, 0.f};
    const float* segA[3] = {P.tmp, P.ch1a, P.ch2a};
    const float* segB[3] = {P.tmp, P.ch1b, P.ch2b};
#pragma unroll
    for (int seg = 0; seg < 3; ++seg) {
        const float* sA = segA[seg];
        const float* sB = segB[seg];
        const size_t wo = (size_t)seg * 66 * kHID;
#pragma unroll 2
        for (int kl = 0; kl < 66; ++kl) {
            float u0 = sA[(size_t)kl * kPc + p];
            float u1 = sB[(size_t)kl * kPc + p];
            float4 w0 = *(const float4*)(wc0 + wo + (size_t)kl * kHID);
            float4 w1 = *(const float4*)(wc1 + wo + (size_t)kl * kHID);
            ac[0] = fmaf(u0, w0.x, ac[0]); ac[1] = fmaf(u0, w0.y, ac[1]);
            ac[2] = fmaf(u0, w0.z, ac[2]); ac[3] = fmaf(u0, w0.w, ac[3]);
            ac[0] = fmaf(u1, w1.x, ac[0]); ac[1] = fmaf(u1, w1.y, ac[1]);
            ac[2] = fmaf(u1, w1.z, ac[2]); ac[3] = fmaf(u1, w1.w, ac[3]);
        }
    }
    const int b = p / kNP, n = p - b * kNP;
    const bool ok = (n < kN);
#pragma unroll
    for (int i = 0; i < 4; ++i) {
        float cn = tanh_f(ac[i] + P.rnb[(rb + 4) * kHID + h0 + i] + P.rnb[(rb + 5) * kHID + h0 + i]);
        float zz = P.zbuf[(size_t)(h0 + i) * kPc + p];
        size_t hidx = (size_t)(2 + h0 + i) * kPc + p;
        float hv = P.xH[hidx];
        if (ok) P.xH[hidx] = zz * hv + (1.f - zz) * cn;
    }
    if (hb == 0 && ok && nextmode != 2) {
        float r0, r1;
        if (nextmode == 0) {
            r0 = P.hist[((b * kL + (t + 1)) * kN + n) * 2 + 0];
            r1 = P.hist[((b * kL + (t + 1)) * kN + n) * 2 + 1];
        } else {
            r0 = 0.f;
            r1 = P.fut[((b * kL + 0) * kN + n) * 2 + 1];
        }
        P.xH[p] = r0;
        P.xH[kPc + p] = r1;
    }
}

// out wave-unit: readout + next dec x rows
__device__ __forceinline__ void d_out(const KParams& P, int t, int u, int lane) {
    const int p = u * 64 + lane;
    const int b = p / kNP, n = p - b * kNP;
    if (n >= kN) return;
    float acc = P.fcb[0];
#pragma unroll
    for (int h = 0; h < kHID; ++h) acc = fmaf(P.xH[(size_t)(2 + h) * kPc + p], P.fcw[h], acc);
    P.out[(b * 12 + t) * kN + n] = acc;
    if (t + 1 < 12) {
        P.xH[p] = acc;
        P.xH[kPc + p] = P.fut[((b * kL + (t + 1)) * kN + n) * 2 + 1];
    }
}

// ---------------------------------------------------------------------------
// cooperative megakernel
__global__ __launch_bounds__(kT, 4) void mega(KParams P) {
    __shared__ SMem sm;
    cg::grid_group grid = cg::this_grid();
    const int lane = threadIdx.x & 63;
    const int wv = threadIdx.x >> 6;
    const int gw = blockIdx.x * 3 + wv;
    const int nw = gridDim.x * 3;
    const int gtid = blockIdx.x * kT + threadIdx.x;
    const int nt = gridDim.x * kT;

    for (int i = gtid; i < kInitT; i += nt) d_init(P, i);
    grid.sync();

    for (int step = 0; step < 24; ++step) {
        const int dec = step >= 12;
        const int t = dec ? step - 12 : step;
        const int hy0 = dec ? 4 : 0;
        const int rb = dec ? 6 : 0;
        const int nextmode = dec ? 2 : (step == 11 ? 1 : 0);

        for (int u = gw; u < kHopU; u += nw)
            d_hop(u, lane, P.adj0, P.adj1, 0, P.xH, P.xH, P.xH, P.hh1a, P.hh1b, cGW);
        grid.sync();
        for (int u = gw; u < kHopU; u += nw)
            d_hop(u, lane, P.adj0, P.adj1, 0, P.hh1a, P.hh1b, P.xH, P.hh2a, P.hh2b, cGW);
        grid.sync();

        for (int vb = blockIdx.x; vb < kMlpAV; vb += gridDim.x) d_mlpA(sm, P, hy0, vb);
        grid.sync();
        for (int vb = blockIdx.x; vb < kMlpBV; vb += gridDim.x) d_mlpB(P, hy0, vb);
        grid.sync();

        for (int u = gw; u < kAdjU; u += nw) d_adj(P, u, lane);
        grid.sync();
        for (int vb = blockIdx.x; vb < kBldEV; vb += gridDim.x) d_buildE(sm, P, vb);
        grid.sync();

        for (int u = gw; u < kHopU; u += nw)
            d_hop(u, lane, P.E0, P.E1, kNN2, P.xH, P.xH, P.xH, P.zh1a, P.zh1b, 1.f);
        grid.sync();
        for (int u = gw; u < kHopU; u += nw)
            d_hop(u, lane, P.E0, P.E1, kNN2, P.zh1a, P.zh1b, P.xH, P.zh2a, P.zh2b, 1.f);
        grid.sync();

        for (int u = gw; u < kGateU; u += nw) d_gates(P, rb, u, lane);
        grid.sync();

        for (int u = gw; u < kHopU; u += nw)
            d_hop(u, lane, P.E0, P.E1, kNN2, P.tmp, P.tmp, P.tmp, P.ch1a, P.ch1b, 1.f);
        grid.sync();
        for (int u = gw; u < kHopU; u += nw)
            d_hop(u, lane, P.E0, P.E1, kNN2, P.ch1a, P.ch1b, P.tmp, P.ch2a, P.ch2b, 1.f);
        grid.sync();

        for (int u = gw; u < kGateU; u += nw) d_final(P, rb, t, nextmode, u, lane);
        grid.sync();

        if (dec) {
            for (int u = gw; u < kOutU; u += nw) d_out(P, t, u, lane);
            grid.sync();
        }
    }
}

// ---------------------------------------------------------------------------
// fallback wrappers (regular launches, same device code)
__global__ __launch_bounds__(kT) void g_init(KParams P) {
    const int gtid = blockIdx.x * kT + threadIdx.x;
    const int nt = gridDim.x * kT;
    for (int i = gtid; i < kInitT; i += nt) d_init(P, i);
}
__global__ __launch_bounds__(kT) void g_hop(const float* Ma, const float* Mb, int mstride,
        const float* hA, const float* hB, const float* xS, float* oA, float* oB, float gamma) {
    const int lane = threadIdx.x & 63;
    const int gw = blockIdx.x * 3 + (threadIdx.x >> 6);
    const int nw = gridDim.x * 3;
    for (int u = gw; u < kHopU; u += nw) d_hop(u, lane, Ma, Mb, mstride, hA, hB, xS, oA, oB, gamma);
}
__global__ __launch_bounds__(kT) void g_mlpA(KParams P, int hy0) {
    __shared__ SMem sm;
    for (int vb = blockIdx.x; vb < kMlpAV; vb += gridDim.x) d_mlpA(sm, P, hy0, vb);
}
__global__ __launch_bounds__(kT) void g_mlpB(KParams P, int hy0) {
    for (int vb = blockIdx.x; vb < kMlpBV; vb += gridDim.x) d_mlpB(P, hy0, vb);
}
__global__ __launch_bounds__(kT) void g_adj(KParams P) {
    const int lane = threadIdx.x & 63;
    const int gw = blockIdx.x * 3 + (threadIdx.x >> 6);
    const int nw = gridDim.x * 3;
    for (int u = gw; u < kAdjU; u += nw) d_adj(P, u, lane);
}
__global__ __launch_bounds__(kT) void g_buildE(KParams P) {
    __shared__ SMem sm;
    for (int vb = blockIdx.x; vb < kBldEV; vb += gridDim.x) d_buildE(sm, P, vb);
}
__global__ __launch_bounds__(kT) void g_gates(KParams P, int rb) {
    const int lane = threadIdx.x & 63;
    const int gw = blockIdx.x * 3 + (threadIdx.x >> 6);
    const int nw = gridDim.x * 3;
    for (int u = gw; u < kGateU; u += nw) d_gates(P, rb, u, lane);
}
__global__ __launch_bounds__(kT) void g_final(KParams P, int rb, int t, int nextmode) {
    const int lane = threadIdx.x & 63;
    const int gw = blockIdx.x * 3 + (threadIdx.x >> 6);
    const int nw = gridDim.x * 3;
    for (int u = gw; u < kGateU; u += nw) d_final(P, rb, t, nextmode, u, lane);
}
__global__ __launch_bounds__(kT) void g_out(KParams P, int t) {
    const int lane = threadIdx.x & 63;
    const int gw = blockIdx.x * 3 + (threadIdx.x >> 6);
    const int nw = gridDim.x * 3;
    for (int u = gw; u < kOutU; u += nw) d_out(P, t, u, lane);
}

// ---------------------------------------------------------------------------
extern "C" void kernel_launch(void* const* d_in, const int* in_sizes, int n_in,
                              void* d_out, int out_size, void* d_ws, size_t ws_size,
                              hipStream_t stream) {
    KParams P;
    P.hist = (const float*)d_in[0];
    P.fut  = (const float*)d_in[1];
    P.adj0 = (const float*)d_in[2];
    P.adj1 = (const float*)d_in[3];
    P.emb1 = (const float*)d_in[4];
    P.emb2 = (const float*)d_in[5];
    P.hw1  = (const float*)d_in[6];
    P.hb1  = (const float*)d_in[7];
    P.hw2  = (const float*)d_in[8];
    P.hb2  = (const float*)d_in[9];
    P.hw3  = (const float*)d_in[10];
    P.hb3  = (const float*)d_in[11];
    P.rnw  = (const float*)d_in[12];
    P.rnb  = (const float*)d_in[13];
    P.fcw  = (const float*)d_in[14];
    P.fcb  = (const float*)d_in[15];
    P.out  = (float*)d_out;

    float* ws = (float*)d_ws;
    const size_t SEG = (size_t)66 * kPc;
    size_t off = 0;
    P.xH   = ws + off; off += SEG;
    P.hh1a = ws + off; off += SEG;
    P.hh1b = ws + off; off += SEG;
    P.hh2a = ws + off; off += SEG;
    P.hh2b = ws + off; off += SEG;
    P.zh1a = ws + off; off += SEG;
    P.zh1b = ws + off; off += SEG;
    P.zh2a = ws + off; off += SEG;
    P.zh2b = ws + off; off += SEG;
    P.tmp  = ws + off; off += SEG;
    P.ch1a = ws + off; off += SEG;
    P.ch1b = ws + off; off += SEG;
    P.ch2a = ws + off; off += SEG;
    P.ch2b = ws + off; off += SEG;
    P.nv1  = ws + off; off += (size_t)kND * kPc;
    P.nv2  = ws + off; off += (size_t)kND * kPc;
    P.zbuf = ws + off; off += (size_t)64 * kPc;
    P.s2g  = ws + off; off += (size_t)8 * kPc;
    P.e1T  = ws + off; off += kND * kN;
    P.e2T  = ws + off; off += kND * kN;
    P.rs   = ws + off; off += kB * kN;
    P.cs   = ws + off; off += kB * kN;
    P.adjv = ws + off; off += (size_t)kB * kNN2;
    P.E0   = ws + off; off += (size_t)kB * kNN2;
    P.E1   = ws + off; off += (size_t)kB * kNN2;

    // occupancy-gated cooperative launch with multi-kernel fallback
    int maxb = 0;
    hipError_t e = hipOccupancyMaxActiveBlocksPerMultiprocessor(&maxb, mega, kT, 0);
    bool coop = (e == hipSuccess) && (maxb * 256 >= kG);
    if (coop) {
        void* args[] = { (void*)&P };
        e = hipLaunchCooperativeKernel((const void*)mega, dim3(kG), dim3(kT), args, 0, stream);
        coop = (e == hipSuccess);
    }
    if (!coop) {
        g_init<<<dim3(kG), dim3(kT), 0, stream>>>(P);
        for (int step = 0; step < 24; ++step) {
            const int dec = step >= 12;
            const int t = dec ? step - 12 : step;
            const int hy0 = dec ? 4 : 0;
            const int rb = dec ? 6 : 0;
            const int nextmode = dec ? 2 : (step == 11 ? 1 : 0);
            g_hop<<<dim3(768), dim3(kT), 0, stream>>>(P.adj0, P.adj1, 0, P.xH, P.xH, P.xH, P.hh1a, P.hh1b, cGW);
            g_hop<<<dim3(768), dim3(kT), 0, stream>>>(P.adj0, P.adj1, 0, P.hh1a, P.hh1b, P.xH, P.hh2a, P.hh2b, cGW);
            g_mlpA<<<dim3(kMlpAV), dim3(kT), 0, stream>>>(P, hy0);
            g_mlpB<<<dim3(kMlpBV), dim3(kT), 0, stream>>>(P, hy0);
            g_adj<<<dim3(1344), dim3(kT), 0, stream>>>(P);
            g_buildE<<<dim3(kBldEV), dim3(kT), 0, stream>>>(P);
            g_hop<<<dim3(768), dim3(kT), 0, stream>>>(P.E0, P.E1, kNN2, P.xH, P.xH, P.xH, P.zh1a, P.zh1b, 1.f);
            g_hop<<<dim3(768), dim3(kT), 0, stream>>>(P.E0, P.E1, kNN2, P.zh1a, P.zh1b, P.xH, P.zh2a, P.zh2b, 1.f);
            g_gates<<<dim3(875), dim3(kT), 0, stream>>>(P, rb);
            g_hop<<<dim3(768), dim3(kT), 0, stream>>>(P.E0, P.E1, kNN2, P.tmp, P.tmp, P.tmp, P.ch1a, P.ch1b, 1.f);
            g_hop<<<dim3(768), dim3(kT), 0, stream>>>(P.E0, P.E1, kNN2, P.ch1a, P.ch1b, P.tmp, P.ch2a, P.ch2b, 1.f);
            g_final<<<dim3(875), dim3(kT), 0, stream>>>(P, rb, t, nextmode);
            if (dec) g_out<<<dim3(55), dim3(kT), 0, stream>>>(P, t);
        }
    }
    (void)in_sizes; (void)n_in; (void)out_size; (void)ws_size;
}

// Round 7
// 11915.990 us; speedup vs baseline: 1.4812x; 1.4812x over previous
//
#include <hip/hip_runtime.h>

// ---- problem constants ----
constexpr int kB   = 32;
constexpr int kL   = 12;
constexpr int kN   = 325;
constexpr int kNP  = 328;          // padded node count
constexpr int kPc  = kB * kNP;     // 10496 column stride, channel-major
constexpr int kHID = 64;
constexpr int kDIN = 198;          // 3 * 66
constexpr int kND  = 40;
constexpr int kNN2 = kN * kN;
constexpr float cAW = 0.05f, cBW = 0.95f, cGW = 0.95f, cTA = 3.0f;

constexpr int kT = 192;            // threads for non-hop kernels (3 waves)
constexpr int kCH = 33;            // channels per hop block (2 cgrps cover 66)

constexpr int kMlpAV  = 765;       // 656 mlp blocks + 109 zero blocks
constexpr int kMlpBV  = 328;
constexpr int kAdjU   = 4032;      // 6 jblk * 21 iblk * 32 b
constexpr int kBldEV  = 1152;      // 6 wblk * 6 vblk * 32 b
constexpr int kGateU  = 2624;      // 164 ptile * 16 hblk
constexpr int kOutU   = 164;
constexpr int kInitT  = 66 * kPc + 2 * kND * kN;

__device__ __forceinline__ float sigm_f(float x) { return 1.f / (1.f + __expf(-x)); }
__device__ __forceinline__ float tanh_f(float x) { return 1.f - 2.f / (1.f + __expf(2.f * x)); }

struct KParams {
    const float *hist, *fut, *adj0, *adj1, *emb1, *emb2;
    const float *hw1, *hb1, *hw2, *hb2, *hw3, *hb3, *rnw, *rnb, *fcw, *fcb;
    float* out;
    float *xH, *hh1a, *hh1b, *hh2a, *hh2b;
    float *zh1a, *zh1b, *zh2a, *zh2b;
    float *tmp, *ch1a, *ch1b, *ch2a, *ch2b;
    float *nv1, *nv2, *zbuf, *s2g, *e1T, *e2T, *rs, *cs, *adjv, *E0, *E1;
};

union SMem {
    float part[2][16][64];   // mlpA partials, 8 KB
    float tile[64][65];      // buildE transpose tile, 16.6 KB
};

// ---------------------------------------------------------------------------
__device__ __forceinline__ void d_init(const KParams& P, int i) {
    if (i < 66 * kPc) {
        int c = i / kPc, p = i - c * kPc;
        int b = p / kNP, n = p - b * kNP;
        if (n < kN) {
            float v = (c < 2) ? P.hist[((b * kL) * kN + n) * 2 + c] : 0.f;
            P.xH[(size_t)c * kPc + p] = v;
        }
    } else {
        int j = i - 66 * kPc;
        if (j < kND * kN) {
            int d = j / kN, n = j - d * kN;
            P.e1T[j] = P.emb1[n * kND + d];
        } else {
            j -= kND * kN;
            int d = j / kN, n = j - d * kN;
            P.e2T[j] = P.emb2[n * kND + d];
        }
    }
}
__global__ __launch_bounds__(kT) void g_init(KParams P) {
    const int gtid = blockIdx.x * kT + threadIdx.x;
    const int nt = gridDim.x * kT;
    for (int i = gtid; i < kInitT; i += nt) d_init(P, i);
}

// ---------------------------------------------------------------------------
// LDS-staged diffusion hop.  out[c,b,w] = gamma*sum_v M[v,w]*h[c,b,v] + AW*x
// grid (6 wblk, 2 cgrp, 64 = sel*32+b), block 256 (4 waves).
// K chunks of 32, double-buffered LDS: M tile [32][64], h slab [33][32].
// All global loads are coalesced vector loads; hot loop reads LDS only
// (M: conflict-free ds_read_b32; h: broadcast ds_read_b128).
__global__ __launch_bounds__(256) void g_hop2(
        const float* __restrict__ Ma, const float* __restrict__ Mb, int mstride,
        const float* __restrict__ hA, const float* __restrict__ hB,
        const float* __restrict__ xS,
        float* __restrict__ oA, float* __restrict__ oB, float gamma) {
    __shared__ float Mt[2][32][64];
    __shared__ float Hs[2][kCH][32];
    const int t = threadIdx.x;
    const int lane = t & 63;
    const int wv = t >> 6;
    const int w0 = blockIdx.x * 64;
    const int c0 = blockIdx.y * kCH;
    const int zb = blockIdx.z;
    const int sel = zb >> 5, b = zb & 31;
    const float* M = (sel ? Mb : Ma) + (size_t)b * mstride;
    const float* h = (sel ? hB : hA) + b * kNP;
    const float* x = xS + b * kNP;
    float* o = (sel ? oB : oA) + b * kNP;
    const int w = w0 + lane;

    const int cw0 = wv * 8;
    const int ccnt = (wv == 3) ? 9 : 8;

    float acc[9];
#pragma unroll
    for (int i = 0; i < 9; ++i) acc[i] = 0.f;

    float mreg[8];
    float hreg[5];

    auto stage_regs = [&](int ck) {
        const int v0 = ck * 32;
#pragma unroll
        for (int i = 0; i < 8; ++i) {
            int idx = i * 256 + t;
            int k = idx >> 6, wcol = idx & 63;
            int v = v0 + k;
            int col = w0 + wcol; if (col >= kN) col = kN - 1;
            mreg[i] = (v < kN) ? M[(size_t)v * kN + col] : 0.f;
        }
#pragma unroll
        for (int i = 0; i < 5; ++i) {
            int idx = i * 256 + t;
            if (idx < kCH * 32) {
                int c = idx >> 5, k = idx & 31;
                int v = v0 + k;
                hreg[i] = (v < kN) ? h[(size_t)(c0 + c) * kPc + v] : 0.f;
            }
        }
    };
    auto write_lds = [&](int bi) {
#pragma unroll
        for (int i = 0; i < 8; ++i) {
            int idx = i * 256 + t;
            Mt[bi][idx >> 6][idx & 63] = mreg[i];
        }
#pragma unroll
        for (int i = 0; i < 5; ++i) {
            int idx = i * 256 + t;
            if (idx < kCH * 32) Hs[bi][idx >> 5][idx & 31] = hreg[i];
        }
    };

    const int nck = (kN + 31) / 32;   // 11
    stage_regs(0);
    write_lds(0);
    for (int ck = 0; ck < nck; ++ck) {
        __syncthreads();                       // staged LDS visible; prev reads done
        if (ck + 1 < nck) stage_regs(ck + 1);  // fire next chunk's global loads
        const int bi = ck & 1;
#pragma unroll
        for (int k4 = 0; k4 < 8; ++k4) {
            float m0 = Mt[bi][k4 * 4 + 0][lane];
            float m1 = Mt[bi][k4 * 4 + 1][lane];
            float m2 = Mt[bi][k4 * 4 + 2][lane];
            float m3 = Mt[bi][k4 * 4 + 3][lane];
#pragma unroll
            for (int c = 0; c < 9; ++c) {
                if (c < ccnt) {
                    float4 hv = *(const float4*)&Hs[bi][cw0 + c][k4 * 4];
                    float s = acc[c];
                    s = fmaf(m0, hv.x, s); s = fmaf(m1, hv.y, s);
                    s = fmaf(m2, hv.z, s); s = fmaf(m3, hv.w, s);
                    acc[c] = s;
                }
            }
        }
        if (ck + 1 < nck) write_lds((ck + 1) & 1);   // other buffer: safe post-compute
    }
    if (w < kN) {
#pragma unroll
        for (int c = 0; c < 9; ++c) {
            if (c < ccnt) {
                size_t idx = (size_t)(c0 + cw0 + c) * kPc + w;
                o[idx] = gamma * acc[c] + cAW * x[idx];
            }
        }
    }
}

// ---------------------------------------------------------------------------
// mlpA virtual block: fc1 (198->16, K-split over 3 waves) + fc2 (16->2) -> s2g
__device__ __forceinline__ void d_mlpA(SMem& sm, const KParams& P, int hy0, int vb) {
    if (vb >= 656) {
        int z = (vb - 656) * kT + threadIdx.x;
        if (z < kB * kN) P.rs[z] = 0.f;
        else if (z < 2 * kB * kN) P.cs[z - kB * kN] = 0.f;
        return;
    }
    const int lane = threadIdx.x & 63;
    const int wv = threadIdx.x >> 6;
    const int pt = vb >> 2, m = vb & 3;
    const int ig = hy0 + m;
    const int p = pt * 64 + lane;
    const float* src = (wv == 0) ? P.xH
                     : (wv == 1) ? ((m & 1) ? P.hh1b : P.hh1a)
                                 : ((m & 1) ? P.hh2b : P.hh2a);
    const float* wp = P.hw1 + (size_t)ig * (kDIN * 16);
    float acc[16];
#pragma unroll
    for (int o = 0; o < 16; ++o) acc[o] = 0.f;
#pragma unroll 2
    for (int kl = 0; kl < 66; ++kl) {
        int kk = wv * 66 + kl;
        float u = src[(size_t)kl * kPc + p];
        float4 wa = *(const float4*)(wp + kk * 16);
        float4 wb = *(const float4*)(wp + kk * 16 + 4);
        float4 wc = *(const float4*)(wp + kk * 16 + 8);
        float4 wd = *(const float4*)(wp + kk * 16 + 12);
        acc[0]  = fmaf(u, wa.x, acc[0]);  acc[1]  = fmaf(u, wa.y, acc[1]);
        acc[2]  = fmaf(u, wa.z, acc[2]);  acc[3]  = fmaf(u, wa.w, acc[3]);
        acc[4]  = fmaf(u, wb.x, acc[4]);  acc[5]  = fmaf(u, wb.y, acc[5]);
        acc[6]  = fmaf(u, wb.z, acc[6]);  acc[7]  = fmaf(u, wb.w, acc[7]);
        acc[8]  = fmaf(u, wc.x, acc[8]);  acc[9]  = fmaf(u, wc.y, acc[9]);
        acc[10] = fmaf(u, wc.z, acc[10]); acc[11] = fmaf(u, wc.w, acc[11]);
        acc[12] = fmaf(u, wd.x, acc[12]); acc[13] = fmaf(u, wd.y, acc[13]);
        acc[14] = fmaf(u, wd.z, acc[14]); acc[15] = fmaf(u, wd.w, acc[15]);
    }
    if (wv > 0) {
#pragma unroll
        for (int o = 0; o < 16; ++o) sm.part[wv - 1][o][lane] = acc[o];
    }
    __syncthreads();
    if (wv == 0) {
        float sv[16];
#pragma unroll
        for (int o = 0; o < 16; ++o)
            sv[o] = sigm_f(P.hb1[ig * 16 + o] + acc[o] + sm.part[0][o][lane] + sm.part[1][o][lane]);
#pragma unroll
        for (int j = 0; j < 2; ++j) {
            float t = P.hb2[ig * 2 + j];
#pragma unroll
            for (int o = 0; o < 16; ++o) t = fmaf(sv[o], P.hw2[ig * 32 + o * 2 + j], t);
            P.s2g[(size_t)(m * 2 + j) * kPc + p] = sigm_f(t);
        }
    }
    __syncthreads();
}
__global__ __launch_bounds__(kT) void g_mlpA(KParams P, int hy0) {
    __shared__ SMem sm;
    for (int vb = blockIdx.x; vb < kMlpAV; vb += gridDim.x) d_mlpA(sm, P, hy0, vb);
}

// mlpB: fc3 (2->40) + combine + nv = tanh(TA*emb*f)
__device__ __forceinline__ void d_mlpB(const KParams& P, int hy0, int vb) {
    const int lane = threadIdx.x & 63;
    const int wv = threadIdx.x >> 6;
    const int sel = vb & 1, pt = vb >> 1;
    const int p = pt * 64 + lane;
    const int b = p / kNP, n = p - b * kNP;
    const int nc = (n < kN) ? n : (kN - 1);
    const bool ok = (n < kN);
    const int i0 = hy0 + sel * 2;
    const int rbase = sel * 4;
    float sa0 = P.s2g[(size_t)(rbase + 0) * kPc + p];
    float sa1 = P.s2g[(size_t)(rbase + 1) * kPc + p];
    float sb0 = P.s2g[(size_t)(rbase + 2) * kPc + p];
    float sb1 = P.s2g[(size_t)(rbase + 3) * kPc + p];
    const float* eT = sel ? P.e2T : P.e1T;
    float* nv = sel ? P.nv2 : P.nv1;
    for (int d = wv; d < kND; d += 3) {
        float f = P.hb3[(i0 + 0) * kND + d] + P.hb3[(i0 + 1) * kND + d]
                + sa0 * P.hw3[(i0 + 0) * 80 + d] + sa1 * P.hw3[(i0 + 0) * 80 + 40 + d]
                + sb0 * P.hw3[(i0 + 1) * 80 + d] + sb1 * P.hw3[(i0 + 1) * 80 + 40 + d];
        float r = tanh_f(cTA * eT[d * kN + nc] * f);
        if (ok) nv[(size_t)d * kPc + p] = r;
    }
}
__global__ __launch_bounds__(kT) void g_mlpB(KParams P, int hy0) {
    for (int vb = blockIdx.x; vb < kMlpBV; vb += gridDim.x) d_mlpB(P, hy0, vb);
}

// ---------------------------------------------------------------------------
// adj wave-unit: adjv[i][j] = relu(tanh(TA*(a_ij - a_ji))) + rs/cs atomics
__device__ __forceinline__ void d_adj(const KParams& P, int u, int lane) {
    const int jblk = u % 6;
    const int rem = u / 6;
    const int iblk = rem % 21;
    const int b = rem / 21;
    const int j = jblk * 64 + lane;
    const bool jok = (j < kN);
    const int jc = jok ? j : (kN - 1);
    const int i0 = iblk * 16;
    const float* p1 = P.nv1 + b * kNP;
    const float* p2 = P.nv2 + b * kNP;
    float aij[16], aji[16];
#pragma unroll
    for (int q = 0; q < 16; ++q) { aij[q] = 0.f; aji[q] = 0.f; }
#pragma unroll 2
    for (int d = 0; d < kND; ++d) {
        const float* r1 = p1 + (size_t)d * kPc;
        const float* r2 = p2 + (size_t)d * kPc;
        float x1j = r1[jc];
        float x2j = r2[jc];
        float4 v1a = *(const float4*)(r1 + i0);
        float4 v1b = *(const float4*)(r1 + i0 + 4);
        float4 v1c = *(const float4*)(r1 + i0 + 8);
        float4 v1d = *(const float4*)(r1 + i0 + 12);
        float4 v2a = *(const float4*)(r2 + i0);
        float4 v2b = *(const float4*)(r2 + i0 + 4);
        float4 v2c = *(const float4*)(r2 + i0 + 8);
        float4 v2d = *(const float4*)(r2 + i0 + 12);
        float w1v[16] = {v1a.x,v1a.y,v1a.z,v1a.w, v1b.x,v1b.y,v1b.z,v1b.w,
                         v1c.x,v1c.y,v1c.z,v1c.w, v1d.x,v1d.y,v1d.z,v1d.w};
        float w2v[16] = {v2a.x,v2a.y,v2a.z,v2a.w, v2b.x,v2b.y,v2b.z,v2b.w,
                         v2c.x,v2c.y,v2c.z,v2c.w, v2d.x,v2d.y,v2d.z,v2d.w};
#pragma unroll
        for (int q = 0; q < 16; ++q) {
            aij[q] = fmaf(w1v[q], x2j, aij[q]);
            aji[q] = fmaf(x1j, w2v[q], aji[q]);
        }
    }
    size_t base = (size_t)b * kNN2;
    float colsum = 0.f;
#pragma unroll
    for (int q = 0; q < 16; ++q) {
        int i = i0 + q;
        float tv = tanh_f(cTA * (aij[q] - aji[q]));
        float av = fmaxf(tv, 0.f);
        bool okk = (i < kN) && jok;
        if (okk) P.adjv[base + (size_t)i * kN + j] = av;
        float rv = okk ? av : 0.f;
        colsum += rv;
        float rsum = rv;
#pragma unroll
        for (int off = 32; off; off >>= 1) rsum += __shfl_down(rsum, off);
        if (lane == 0 && i < kN) atomicAdd(&P.rs[b * kN + i], rsum);
    }
    if (jok) atomicAdd(&P.cs[b * kN + j], colsum);
}
__global__ __launch_bounds__(kT) void g_adj(KParams P) {
    const int lane = threadIdx.x & 63;
    const int gw = blockIdx.x * 3 + (threadIdx.x >> 6);
    const int nw = gridDim.x * 3;
    for (int u = gw; u < kAdjU; u += nw) d_adj(P, u, lane);
}

// ---------------------------------------------------------------------------
// buildE virtual block: E0/E1 with tiled transpose
__device__ __forceinline__ void d_buildE(SMem& sm, const KParams& P, int vb) {
    const int lane = threadIdx.x & 63;
    const int wv = threadIdx.x >> 6;
    const int w0 = (vb % 6) * 64;
    const int v0 = ((vb / 6) % 6) * 64;
    const int b = vb / 36;
    const float* av = P.adjv + (size_t)b * kNN2;
    for (int r = wv; r < 64; r += 3) {
        int v = v0 + r, w = w0 + lane;
        sm.tile[r][lane] = (v < kN && w < kN) ? av[(size_t)v * kN + w] : 0.f;
    }
    __syncthreads();
    size_t eb = (size_t)b * kNN2;
    for (int r = wv; r < 64; r += 3) {
        {
            int v = v0 + r, w = w0 + lane;
            if (v < kN && w < kN) {
                float iv = 1.f / (1.f + P.rs[b * kN + v]);
                float e = cBW * sm.tile[r][lane] * iv + cGW * P.adj0[v * kN + w];
                if (v == w) e += cBW * iv;
                P.E0[eb + (size_t)v * kN + w] = e;
            }
        }
        {
            int v = w0 + r, w = v0 + lane;
            if (v < kN && w < kN) {
                float iv = 1.f / (1.f + P.cs[b * kN + v]);
                float e = cBW * sm.tile[lane][r] * iv + cGW * P.adj1[v * kN + w];
                if (v == w) e += cBW * iv;
                P.E1[eb + (size_t)v * kN + w] = e;
            }
        }
    }
    __syncthreads();
}
__global__ __launch_bounds__(kT) void g_buildE(KParams P) {
    __shared__ SMem sm;
    for (int vb = blockIdx.x; vb < kBldEV; vb += gridDim.x) d_buildE(sm, P, vb);
}

// ---------------------------------------------------------------------------
// gates wave-unit: z,r + tmp=[x, r*H]
__device__ __forceinline__ void d_gates(const KParams& P, int rb, int u, int lane) {
    const int pt = u % 164, hb = u / 164;
    const int p = pt * 64 + lane;
    const int h0 = hb * 4;
    const float* wz0 = P.rnw + (size_t)(rb + 0) * (kDIN * kHID) + h0;
    const float* wz1 = P.rnw + (size_t)(rb + 1) * (kDIN * kHID) + h0;
    const float* wr0 = P.rnw + (size_t)(rb + 2) * (kDIN * kHID) + h0;
    const float* wr1 = P.rnw + (size_t)(rb + 3) * (kDIN * kHID) + h0;
    float az[4] = {0.f, 0.f, 0.f, 0.f}, ar[4] = {0.f, 0.f, 0.f, 0.f};
    const float* segA[3] = {P.xH, P.zh1a, P.zh2a};
    const float* segB[3] = {P.xH, P.zh1b, P.zh2b};
#pragma unroll
    for (int seg = 0; seg < 3; ++seg) {
        const float* sA = segA[seg];
        const float* sB = segB[seg];
        const size_t wo = (size_t)seg * 66 * kHID;
#pragma unroll 2
        for (int kl = 0; kl < 66; ++kl) {
            float u0 = sA[(size_t)kl * kPc + p];
            float u1 = sB[(size_t)kl * kPc + p];
            float4 z0 = *(const float4*)(wz0 + wo + (size_t)kl * kHID);
            float4 z1 = *(const float4*)(wz1 + wo + (size_t)kl * kHID);
            float4 r0 = *(const float4*)(wr0 + wo + (size_t)kl * kHID);
            float4 r1 = *(const float4*)(wr1 + wo + (size_t)kl * kHID);
            az[0] = fmaf(u0, z0.x, az[0]); az[1] = fmaf(u0, z0.y, az[1]);
            az[2] = fmaf(u0, z0.z, az[2]); az[3] = fmaf(u0, z0.w, az[3]);
            az[0] = fmaf(u1, z1.x, az[0]); az[1] = fmaf(u1, z1.y, az[1]);
            az[2] = fmaf(u1, z1.z, az[2]); az[3] = fmaf(u1, z1.w, az[3]);
            ar[0] = fmaf(u0, r0.x, ar[0]); ar[1] = fmaf(u0, r0.y, ar[1]);
            ar[2] = fmaf(u0, r0.z, ar[2]); ar[3] = fmaf(u0, r0.w, ar[3]);
            ar[0] = fmaf(u1, r1.x, ar[0]); ar[1] = fmaf(u1, r1.y, ar[1]);
            ar[2] = fmaf(u1, r1.z, ar[2]); ar[3] = fmaf(u1, r1.w, ar[3]);
        }
    }
    const int b = p / kNP, n = p - b * kNP;
    const bool ok = (n < kN);
#pragma unroll
    for (int i = 0; i < 4; ++i) {
        float zz = sigm_f(az[i] + P.rnb[(rb + 0) * kHID + h0 + i] + P.rnb[(rb + 1) * kHID + h0 + i]);
        float rr = sigm_f(ar[i] + P.rnb[(rb + 2) * kHID + h0 + i] + P.rnb[(rb + 3) * kHID + h0 + i]);
        float tv = rr * P.xH[(size_t)(2 + h0 + i) * kPc + p];
        if (ok) {
            P.zbuf[(size_t)(h0 + i) * kPc + p] = zz;
            P.tmp[(size_t)(2 + h0 + i) * kPc + p] = tv;
        }
    }
    if (hb == 0 && ok) {
        P.tmp[p] = P.xH[p];
        P.tmp[kPc + p] = P.xH[kPc + p];
    }
}
__global__ __launch_bounds__(kT) void g_gates(KParams P, int rb) {
    const int lane = threadIdx.x & 63;
    const int gw = blockIdx.x * 3 + (threadIdx.x >> 6);
    const int nw = gridDim.x * 3;
    for (int u = gw; u < kGateU; u += nw) d_gates(P, rb, u, lane);
}

// ---------------------------------------------------------------------------
// final wave-unit: Cn + GRU update in place + next-step x rows
__device__ __forceinline__ void d_final(const KParams& P, int rb, int t, int nextmode,
                                        int u, int lane) {
    const int pt = u % 164, hb = u / 164;
    const int p = pt * 64 + lane;
    const int h0 = hb * 4;
    const float* wc0 = P.rnw + (size_t)(rb + 4) * (kDIN * kHID) + h0;
    const float* wc1 = P.rnw + (size_t)(rb + 5) * (kDIN * kHID) + h0;
    float ac[4] = {0.f, 0.f, 0.f, 0.f};
    const float* segA[3] = {P.tmp, P.ch1a, P.ch2a};
    const float* segB[3] = {P.tmp, P.ch1b, P.ch2b};
#pragma unroll
    for (int seg = 0; seg < 3; ++seg) {
        const float* sA = segA[seg];
        const float* sB = segB[seg];
        const size_t wo = (size_t)seg * 66 * kHID;
#pragma unroll 2
        for (int kl = 0; kl < 66; ++kl) {
            float u0 = sA[(size_t)kl * kPc + p];
            float u1 = sB[(size_t)kl * kPc + p];
            float4 w0 = *(const float4*)(wc0 + wo + (size_t)kl * kHID);
            float4 w1 = *(const float4*)(wc1 + wo + (size_t)kl * kHID);
            ac[0] = fmaf(u0, w0.x, ac[0]); ac[1] = fmaf(u0, w0.y, ac[1]);
            ac[2] = fmaf(u0, w0.z, ac[2]); ac[3] = fmaf(u0, w0.w, ac[3]);
            ac[0] = fmaf(u1, w1.x, ac[0]); ac[1] = fmaf(u1, w1.y, ac[1]);
            ac[2] = fmaf(u1, w1.z, ac[2]); ac[3] = fmaf(u1, w1.w, ac[3]);
        }
    }
    const int b = p / kNP, n = p - b * kNP;
    const bool ok = (n < kN);
#pragma unroll
    for (int i = 0; i < 4; ++i) {
        float cn = tanh_f(ac[i] + P.rnb[(rb + 4) * kHID + h0 + i] + P.rnb[(rb + 5) * kHID + h0 + i]);
        float zz = P.zbuf[(size_t)(h0 + i) * kPc + p];
        size_t hidx = (size_t)(2 + h0 + i) * kPc + p;
        float hv = P.xH[hidx];
        if (ok) P.xH[hidx] = zz * hv + (1.f - zz) * cn;
    }
    if (hb == 0 && ok && nextmode != 2) {
        float r0, r1;
        if (nextmode == 0) {
            r0 = P.hist[((b * kL + (t + 1)) * kN + n) * 2 + 0];
            r1 = P.hist[((b * kL + (t + 1)) * kN + n) * 2 + 1];
        } else {
            r0 = 0.f;
            r1 = P.fut[((b * kL + 0) * kN + n) * 2 + 1];
        }
        P.xH[p] = r0;
        P.xH[kPc + p] = r1;
    }
}
__global__ __launch_bounds__(kT) void g_final(KParams P, int rb, int t, int nextmode) {
    const int lane = threadIdx.x & 63;
    const int gw = blockIdx.x * 3 + (threadIdx.x >> 6);
    const int nw = gridDim.x * 3;
    for (int u = gw; u < kGateU; u += nw) d_final(P, rb, t, nextmode, u, lane);
}

// out wave-unit: readout + next dec x rows
__device__ __forceinline__ void d_out(const KParams& P, int t, int u, int lane) {
    const int p = u * 64 + lane;
    const int b = p / kNP, n = p - b * kNP;
    if (n >= kN) return;
    float acc = P.fcb[0];
#pragma unroll
    for (int h = 0; h < kHID; ++h) acc = fmaf(P.xH[(size_t)(2 + h) * kPc + p], P.fcw[h], acc);
    P.out[(b * 12 + t) * kN + n] = acc;
    if (t + 1 < 12) {
        P.xH[p] = acc;
        P.xH[kPc + p] = P.fut[((b * kL + (t + 1)) * kN + n) * 2 + 1];
    }
}
__global__ __launch_bounds__(kT) void g_out(KParams P, int t) {
    const int lane = threadIdx.x & 63;
    const int gw = blockIdx.x * 3 + (threadIdx.x >> 6);
    const int nw = gridDim.x * 3;
    for (int u = gw; u < kOutU; u += nw) d_out(P, t, u, lane);
}

// ---------------------------------------------------------------------------
extern "C" void kernel_launch(void* const* d_in, const int* in_sizes, int n_in,
                              void* d_out, int out_size, void* d_ws, size_t ws_size,
                              hipStream_t stream) {
    KParams P;
    P.hist = (const float*)d_in[0];
    P.fut  = (const float*)d_in[1];
    P.adj0 = (const float*)d_in[2];
    P.adj1 = (const float*)d_in[3];
    P.emb1 = (const float*)d_in[4];
    P.emb2 = (const float*)d_in[5];
    P.hw1  = (const float*)d_in[6];
    P.hb1  = (const float*)d_in[7];
    P.hw2  = (const float*)d_in[8];
    P.hb2  = (const float*)d_in[9];
    P.hw3  = (const float*)d_in[10];
    P.hb3  = (const float*)d_in[11];
    P.rnw  = (const float*)d_in[12];
    P.rnb  = (const float*)d_in[13];
    P.fcw  = (const float*)d_in[14];
    P.fcb  = (const float*)d_in[15];
    P.out  = (float*)d_out;

    float* ws = (float*)d_ws;
    const size_t SEG = (size_t)66 * kPc;
    size_t off = 0;
    P.xH   = ws + off; off += SEG;
    P.hh1a = ws + off; off += SEG;
    P.hh1b = ws + off; off += SEG;
    P.hh2a = ws + off; off += SEG;
    P.hh2b = ws + off; off += SEG;
    P.zh1a = ws + off; off += SEG;
    P.zh1b = ws + off; off += SEG;
    P.zh2a = ws + off; off += SEG;
    P.zh2b = ws + off; off += SEG;
    P.tmp  = ws + off; off += SEG;
    P.ch1a = ws + off; off += SEG;
    P.ch1b = ws + off; off += SEG;
    P.ch2a = ws + off; off += SEG;
    P.ch2b = ws + off; off += SEG;
    P.nv1  = ws + off; off += (size_t)kND * kPc;
    P.nv2  = ws + off; off += (size_t)kND * kPc;
    P.zbuf = ws + off; off += (size_t)64 * kPc;
    P.s2g  = ws + off; off += (size_t)8 * kPc;
    P.e1T  = ws + off; off += kND * kN;
    P.e2T  = ws + off; off += kND * kN;
    P.rs   = ws + off; off += kB * kN;
    P.cs   = ws + off; off += kB * kN;
    P.adjv = ws + off; off += (size_t)kB * kNN2;
    P.E0   = ws + off; off += (size_t)kB * kNN2;
    P.E1   = ws + off; off += (size_t)kB * kNN2;

    const dim3 HG(6, 2, 64), HB(256);

    g_init<<<dim3(1024), dim3(kT), 0, stream>>>(P);
    for (int step = 0; step < 24; ++step) {
        const int dec = step >= 12;
        const int t = dec ? step - 12 : step;
        const int hy0 = dec ? 4 : 0;
        const int rb = dec ? 6 : 0;
        const int nextmode = dec ? 2 : (step == 11 ? 1 : 0);

        g_hop2<<<HG, HB, 0, stream>>>(P.adj0, P.adj1, 0, P.xH, P.xH, P.xH, P.hh1a, P.hh1b, cGW);
        g_hop2<<<HG, HB, 0, stream>>>(P.adj0, P.adj1, 0, P.hh1a, P.hh1b, P.xH, P.hh2a, P.hh2b, cGW);

        g_mlpA<<<dim3(kMlpAV), dim3(kT), 0, stream>>>(P, hy0);
        g_mlpB<<<dim3(kMlpBV), dim3(kT), 0, stream>>>(P, hy0);

        g_adj<<<dim3(1344), dim3(kT), 0, stream>>>(P);
        g_buildE<<<dim3(kBldEV), dim3(kT), 0, stream>>>(P);

        g_hop2<<<HG, HB, 0, stream>>>(P.E0, P.E1, kNN2, P.xH, P.xH, P.xH, P.zh1a, P.zh1b, 1.f);
        g_hop2<<<HG, HB, 0, stream>>>(P.E0, P.E1, kNN2, P.zh1a, P.zh1b, P.xH, P.zh2a, P.zh2b, 1.f);

        g_gates<<<dim3(875), dim3(kT), 0, stream>>>(P, rb);

        g_hop2<<<HG, HB, 0, stream>>>(P.E0, P.E1, kNN2, P.tmp, P.tmp, P.tmp, P.ch1a, P.ch1b, 1.f);
        g_hop2<<<HG, HB, 0, stream>>>(P.E0, P.E1, kNN2, P.ch1a, P.ch1b, P.tmp, P.ch2a, P.ch2b, 1.f);

        g_final<<<dim3(875), dim3(kT), 0, stream>>>(P, rb, t, nextmode);

        if (dec) g_out<<<dim3(55), dim3(kT), 0, stream>>>(P, t);
    }
    (void)in_sizes; (void)n_in; (void)out_size; (void)ws_size;
}

// Round 9
// 11786.799 us; speedup vs baseline: 1.4974x; 1.0110x over previous
//
#include <hip/hip_runtime.h>

typedef unsigned short ushort_t;

// ---- problem constants ----
constexpr int kB   = 32;
constexpr int kL   = 12;
constexpr int kN   = 325;
constexpr int kNP  = 328;          // padded node count
constexpr int kPc  = kB * kNP;     // 10496 column stride, channel-major
constexpr int kHID = 64;
constexpr int kDIN = 198;          // 3 * 66
constexpr int kND  = 40;
constexpr int kNN2 = kN * kN;
constexpr float cAW = 0.05f, cBW = 0.95f, cGW = 0.95f, cTA = 3.0f;

constexpr int kT = 192;            // threads for non-hop kernels (3 waves)
constexpr int kWs = 384;           // transposed-E w rows (6 strips x 64)
constexpr int kVs = 352;           // transposed-E v stride (11*32 = 352, padded, mult 8)
constexpr int kETb = kWs * kVs;    // per-b elements = 135168

constexpr int kMlpAV  = 765;       // 656 mlp blocks + 109 zero blocks
constexpr int kMlpBV  = 328;
constexpr int kAdjU   = 4032;      // 6 jblk * 21 iblk * 32 b
constexpr int kBldEV  = 1152;      // 6 wblk * 6 vblk * 32 b
constexpr int kGateU  = 2624;      // 164 ptile * 16 hblk
constexpr int kOutU   = 164;

// init index-space regions
constexpr int kInit1 = 66 * kPc;                    // xH
constexpr int kInit2 = 2 * kND * kN;                // e1T/e2T
constexpr int kInit3 = 2 * kETb;                    // a0T/a1T hi/lo/f
constexpr int kInit4 = 4 * kB * kETb / 2;           // zero E0h..E1l as uints
constexpr int kInitT = kInit1 + kInit2 + kInit3 + kInit4;

using short8 = __attribute__((ext_vector_type(8))) short;
using f32x4  = __attribute__((ext_vector_type(4))) float;
union ABu { ushort_t u[8]; short8 v; };

__device__ __forceinline__ float sigm_f(float x) { return 1.f / (1.f + __expf(-x)); }
__device__ __forceinline__ float tanh_f(float x) { return 1.f - 2.f / (1.f + __expf(2.f * x)); }
__device__ __forceinline__ ushort_t f2b(float x) {   // fp32 -> bf16 RNE
    union { float f; unsigned u; } c; c.f = x;
    unsigned r = c.u + 0x7FFFu + ((c.u >> 16) & 1u);
    return (ushort_t)(r >> 16);
}
__device__ __forceinline__ float b2f(ushort_t h) {
    union { unsigned u; float f; } c; c.u = ((unsigned)h) << 16; return c.f;
}
__device__ __forceinline__ void split_bf(float x, ushort_t& hi, ushort_t& lo) {
    hi = f2b(x);
    lo = f2b(x - b2f(hi));
}

struct KParams {
    const float *hist, *fut, *adj0, *adj1, *emb1, *emb2;
    const float *hw1, *hb1, *hw2, *hb2, *hw3, *hb3, *rnw, *rnb, *fcw, *fcb;
    float* out;
    float *xH, *hA1, *hB1, *hA2, *hB2, *tmp;              // 6 SEG h-buffers
    float *nv1, *nv2, *zbuf, *s2g, *e1T, *e2T, *rs, *cs, *adjv;
    float *a0Tf, *a1Tf;                                   // fp32 transposed adj [w][v]
    ushort_t *E0h, *E0l, *E1h, *E1l;                      // bf16 hi/lo E^T [b][w][v]
    ushort_t *a0h, *a0l, *a1h, *a1l;                      // bf16 hi/lo adj^T [w][v]
};

// ---------------------------------------------------------------------------
__device__ __forceinline__ void d_init(const KParams& P, int i) {
    if (i < kInit1) {
        int c = i / kPc, p = i - c * kPc;
        int b = p / kNP, n = p - b * kNP;
        if (n < kN) {
            float v = (c < 2) ? P.hist[((b * kL) * kN + n) * 2 + c] : 0.f;
            P.xH[(size_t)c * kPc + p] = v;
        }
        return;
    }
    int j = i - kInit1;
    if (j < kND * kN) { int d = j / kN, n = j - d * kN; P.e1T[j] = P.emb1[n * kND + d]; return; }
    j -= kND * kN;
    if (j < kND * kN) { int d = j / kN, n = j - d * kN; P.e2T[j] = P.emb2[n * kND + d]; return; }
    j -= kND * kN;
    if (j < kInit3) {
        int m = j / kETb, idx = j - m * kETb;
        int w = idx / kVs, v = idx - w * kVs;
        const float* adj = m ? P.adj1 : P.adj0;
        float val = (w < kN && v < kN) ? adj[(size_t)v * kN + w] : 0.f;
        ushort_t hi, lo; split_bf(val, hi, lo);
        if (m) { P.a1h[idx] = hi; P.a1l[idx] = lo; P.a1Tf[idx] = val; }
        else   { P.a0h[idx] = hi; P.a0l[idx] = lo; P.a0Tf[idx] = val; }
        return;
    }
    j -= kInit3;
    if (j < kInit4) ((unsigned*)P.E0h)[j] = 0;   // E0h,E0l,E1h,E1l contiguous
}
__global__ __launch_bounds__(kT) void g_init(KParams P) {
    const int gtid = blockIdx.x * kT + threadIdx.x;
    const int nt = gridDim.x * kT;
    for (int i = gtid; i < kInitT; i += nt) d_init(P, i);
}

// ---------------------------------------------------------------------------
// Split-bf16 MFMA diffusion hop (no LDS, no barriers).
// out[c,b,w] = gamma * sum_v M[v,w]*h[c,b,v] + AW*x[c,b,w]
// M given as transposed bf16 hi/lo: MT[w][v], v-stride kVs, pads zero.
// grid (6 wstrip, 5 ctile, 64 = sel*32+b), block 64 (1 wave).
// A-frag: A[m=lane&15][k=quad*8+j] (channel m, v k); B-frag: B[k][n=lane&15]
// via 16B loads from MT row w.  C/D: row=quad*4+r (channel), col=lane&15 (w).
__global__ __launch_bounds__(64) void g_hopm(
        const ushort_t* __restrict__ MaH, const ushort_t* __restrict__ MaL,
        const ushort_t* __restrict__ MbH, const ushort_t* __restrict__ MbL,
        int mstride,
        const float* __restrict__ hA, const float* __restrict__ hB,
        const float* __restrict__ xS,
        float* __restrict__ oA, float* __restrict__ oB, float gamma) {
    const int lane = threadIdx.x;
    const int quad = lane >> 4, ln15 = lane & 15;
    const int w0 = blockIdx.x * 64;
    const int ct = blockIdx.y;
    const int zb = blockIdx.z;
    const int sel = zb >> 5, b = zb & 31;
    const ushort_t* EH = (sel ? MbH : MaH) + (size_t)b * mstride;
    const ushort_t* EL = (sel ? MbL : MaL) + (size_t)b * mstride;
    const float* hb = (sel ? hB : hA) + b * kNP;
    const float* xb = xS + b * kNP;
    float* ob = (sel ? oB : oA) + b * kNP;
    const int ac = ct * 16 + ln15;                 // A channel for this lane
    const float* ap = hb + (size_t)ac * kPc + quad * 8;
    size_t brow[4];
#pragma unroll
    for (int nn = 0; nn < 4; ++nn)
        brow[nn] = (size_t)(w0 + nn * 16 + ln15) * kVs + quad * 8;

    f32x4 acc[4];
#pragma unroll
    for (int nn = 0; nn < 4; ++nn) acc[nn] = f32x4{0.f, 0.f, 0.f, 0.f};

    for (int ks = 0; ks < 11; ++ks) {
        const int v0 = ks * 32;
        float4 f0 = *(const float4*)(ap + v0);
        float4 f1 = *(const float4*)(ap + v0 + 4);
        float fs[8] = {f0.x, f0.y, f0.z, f0.w, f1.x, f1.y, f1.z, f1.w};
        ABu ah, al;
#pragma unroll
        for (int j = 0; j < 8; ++j) {
            ushort_t hi = f2b(fs[j]);
            ah.u[j] = hi;
            al.u[j] = f2b(fs[j] - b2f(hi));
        }
#pragma unroll
        for (int nn = 0; nn < 4; ++nn) {
            short8 bh = *(const short8*)(EH + brow[nn] + v0);
            short8 bl = *(const short8*)(EL + brow[nn] + v0);
            acc[nn] = __builtin_amdgcn_mfma_f32_16x16x32_bf16(ah.v, bh, acc[nn], 0, 0, 0);
            acc[nn] = __builtin_amdgcn_mfma_f32_16x16x32_bf16(al.v, bh, acc[nn], 0, 0, 0);
            acc[nn] = __builtin_amdgcn_mfma_f32_16x16x32_bf16(ah.v, bl, acc[nn], 0, 0, 0);
        }
    }
#pragma unroll
    for (int nn = 0; nn < 4; ++nn) {
        int w = w0 + nn * 16 + ln15;
        if (w < kN) {
#pragma unroll
            for (int r = 0; r < 4; ++r) {
                int c = ct * 16 + quad * 4 + r;
                if (c < 66) {
                    size_t idx = (size_t)c * kPc + w;
                    ob[idx] = gamma * acc[nn][r] + cAW * xb[idx];
                }
            }
        }
    }
}

// ---------------------------------------------------------------------------
// mlpA virtual block: fc1 (198->16, K-split over 3 waves) + fc2 (16->2) -> s2g
__global__ __launch_bounds__(kT) void g_mlpA(KParams P, int hy0) {
    __shared__ float part[2][16][64];
    for (int vb = blockIdx.x; vb < kMlpAV; vb += gridDim.x) {
        if (vb >= 656) {
            int z = (vb - 656) * kT + threadIdx.x;
            if (z < kB * kN) P.rs[z] = 0.f;
            else if (z < 2 * kB * kN) P.cs[z - kB * kN] = 0.f;
            continue;
        }
        const int lane = threadIdx.x & 63;
        const int wv = threadIdx.x >> 6;
        const int pt = vb >> 2, m = vb & 3;
        const int ig = hy0 + m;
        const int p = pt * 64 + lane;
        const float* src = (wv == 0) ? P.xH
                         : (wv == 1) ? ((m & 1) ? P.hB1 : P.hA1)
                                     : ((m & 1) ? P.hB2 : P.hA2);
        const float* wp = P.hw1 + (size_t)ig * (kDIN * 16);
        float acc[16];
#pragma unroll
        for (int o = 0; o < 16; ++o) acc[o] = 0.f;
#pragma unroll 2
        for (int kl = 0; kl < 66; ++kl) {
            int kk = wv * 66 + kl;
            float u = src[(size_t)kl * kPc + p];
            float4 wa = *(const float4*)(wp + kk * 16);
            float4 wb = *(const float4*)(wp + kk * 16 + 4);
            float4 wc = *(const float4*)(wp + kk * 16 + 8);
            float4 wd = *(const float4*)(wp + kk * 16 + 12);
            acc[0]  = fmaf(u, wa.x, acc[0]);  acc[1]  = fmaf(u, wa.y, acc[1]);
            acc[2]  = fmaf(u, wa.z, acc[2]);  acc[3]  = fmaf(u, wa.w, acc[3]);
            acc[4]  = fmaf(u, wb.x, acc[4]);  acc[5]  = fmaf(u, wb.y, acc[5]);
            acc[6]  = fmaf(u, wb.z, acc[6]);  acc[7]  = fmaf(u, wb.w, acc[7]);
            acc[8]  = fmaf(u, wc.x, acc[8]);  acc[9]  = fmaf(u, wc.y, acc[9]);
            acc[10] = fmaf(u, wc.z, acc[10]); acc[11] = fmaf(u, wc.w, acc[11]);
            acc[12] = fmaf(u, wd.x, acc[12]); acc[13] = fmaf(u, wd.y, acc[13]);
            acc[14] = fmaf(u, wd.z, acc[14]); acc[15] = fmaf(u, wd.w, acc[15]);
        }
        if (wv > 0) {
#pragma unroll
            for (int o = 0; o < 16; ++o) part[wv - 1][o][lane] = acc[o];
        }
        __syncthreads();
        if (wv == 0) {
            float sv[16];
#pragma unroll
            for (int o = 0; o < 16; ++o)
                sv[o] = sigm_f(P.hb1[ig * 16 + o] + acc[o] + part[0][o][lane] + part[1][o][lane]);
#pragma unroll
            for (int j = 0; j < 2; ++j) {
                float t = P.hb2[ig * 2 + j];
#pragma unroll
                for (int o = 0; o < 16; ++o) t = fmaf(sv[o], P.hw2[ig * 32 + o * 2 + j], t);
                P.s2g[(size_t)(m * 2 + j) * kPc + p] = sigm_f(t);
            }
        }
        __syncthreads();
    }
}

// mlpB: fc3 (2->40) + combine + nv = tanh(TA*emb*f)
__global__ __launch_bounds__(kT) void g_mlpB(KParams P, int hy0) {
    for (int vb = blockIdx.x; vb < kMlpBV; vb += gridDim.x) {
        const int lane = threadIdx.x & 63;
        const int wv = threadIdx.x >> 6;
        const int sel = vb & 1, pt = vb >> 1;
        const int p = pt * 64 + lane;
        const int b = p / kNP, n = p - b * kNP;
        const int nc = (n < kN) ? n : (kN - 1);
        const bool ok = (n < kN);
        const int i0 = hy0 + sel * 2;
        const int rbase = sel * 4;
        float sa0 = P.s2g[(size_t)(rbase + 0) * kPc + p];
        float sa1 = P.s2g[(size_t)(rbase + 1) * kPc + p];
        float sb0 = P.s2g[(size_t)(rbase + 2) * kPc + p];
        float sb1 = P.s2g[(size_t)(rbase + 3) * kPc + p];
        const float* eT = sel ? P.e2T : P.e1T;
        float* nv = sel ? P.nv2 : P.nv1;
        for (int d = wv; d < kND; d += 3) {
            float f = P.hb3[(i0 + 0) * kND + d] + P.hb3[(i0 + 1) * kND + d]
                    + sa0 * P.hw3[(i0 + 0) * 80 + d] + sa1 * P.hw3[(i0 + 0) * 80 + 40 + d]
                    + sb0 * P.hw3[(i0 + 1) * 80 + d] + sb1 * P.hw3[(i0 + 1) * 80 + 40 + d];
            float r = tanh_f(cTA * eT[d * kN + nc] * f);
            if (ok) nv[(size_t)d * kPc + p] = r;
        }
    }
}

// ---------------------------------------------------------------------------
// adj wave-unit: adjv[i][j] = relu(tanh(TA*(a_ij - a_ji))) + rs/cs atomics
__device__ __forceinline__ void d_adj(const KParams& P, int u, int lane) {
    const int jblk = u % 6;
    const int rem = u / 6;
    const int iblk = rem % 21;
    const int b = rem / 21;
    const int j = jblk * 64 + lane;
    const bool jok = (j < kN);
    const int jc = jok ? j : (kN - 1);
    const int i0 = iblk * 16;
    const float* p1 = P.nv1 + b * kNP;
    const float* p2 = P.nv2 + b * kNP;
    float aij[16], aji[16];
#pragma unroll
    for (int q = 0; q < 16; ++q) { aij[q] = 0.f; aji[q] = 0.f; }
#pragma unroll 2
    for (int d = 0; d < kND; ++d) {
        const float* r1 = p1 + (size_t)d * kPc;
        const float* r2 = p2 + (size_t)d * kPc;
        float x1j = r1[jc];
        float x2j = r2[jc];
        float4 v1a = *(const float4*)(r1 + i0);
        float4 v1b = *(const float4*)(r1 + i0 + 4);
        float4 v1c = *(const float4*)(r1 + i0 + 8);
        float4 v1d = *(const float4*)(r1 + i0 + 12);
        float4 v2a = *(const float4*)(r2 + i0);
        float4 v2b = *(const float4*)(r2 + i0 + 4);
        float4 v2c = *(const float4*)(r2 + i0 + 8);
        float4 v2d = *(const float4*)(r2 + i0 + 12);
        float w1v[16] = {v1a.x,v1a.y,v1a.z,v1a.w, v1b.x,v1b.y,v1b.z,v1b.w,
                         v1c.x,v1c.y,v1c.z,v1c.w, v1d.x,v1d.y,v1d.z,v1d.w};
        float w2v[16] = {v2a.x,v2a.y,v2a.z,v2a.w, v2b.x,v2b.y,v2b.z,v2b.w,
                         v2c.x,v2c.y,v2c.z,v2c.w, v2d.x,v2d.y,v2d.z,v2d.w};
#pragma unroll
        for (int q = 0; q < 16; ++q) {
            aij[q] = fmaf(w1v[q], x2j, aij[q]);
            aji[q] = fmaf(x1j, w2v[q], aji[q]);
        }
    }
    size_t base = (size_t)b * kNN2;
    float colsum = 0.f;
#pragma unroll
    for (int q = 0; q < 16; ++q) {
        int i = i0 + q;
        float tv = tanh_f(cTA * (aij[q] - aji[q]));
        float av = fmaxf(tv, 0.f);
        bool okk = (i < kN) && jok;
        if (okk) P.adjv[base + (size_t)i * kN + j] = av;
        float rv = okk ? av : 0.f;
        colsum += rv;
        float rsum = rv;
#pragma unroll
        for (int off = 32; off; off >>= 1) rsum += __shfl_down(rsum, off);
        if (lane == 0 && i < kN) atomicAdd(&P.rs[b * kN + i], rsum);
    }
    if (jok) atomicAdd(&P.cs[b * kN + j], colsum);
}
__global__ __launch_bounds__(kT) void g_adj(KParams P) {
    const int lane = threadIdx.x & 63;
    const int gw = blockIdx.x * 3 + (threadIdx.x >> 6);
    const int nw = gridDim.x * 3;
    for (int u = gw; u < kAdjU; u += nw) d_adj(P, u, lane);
}

// ---------------------------------------------------------------------------
// buildE: writes transposed bf16 hi/lo E0/E1: E^T[b][w][v], v-stride kVs.
// E0[v][w] = BW*(adjv[v][w]+I)/(1+rs[v]) + GW*adj0[v][w]
// E1[v][w] = BW*(adjv[w][v]+I)/(1+cs[v]) + GW*adj1[v][w]
__global__ __launch_bounds__(kT) void g_buildE(KParams P) {
    __shared__ float tA[64][65];
    __shared__ float tB[64][65];
    for (int vb = blockIdx.x; vb < kBldEV; vb += gridDim.x) {
        const int lane = threadIdx.x & 63;
        const int wv = threadIdx.x >> 6;
        const int w0 = (vb % 6) * 64;
        const int v0 = ((vb / 6) % 6) * 64;
        const int b = vb / 36;
        const float* av = P.adjv + (size_t)b * kNN2;
        for (int r = wv; r < 64; r += 3) {
            int v = v0 + r, w = w0 + lane;
            tA[r][lane] = (v < kN && w < kN) ? av[(size_t)v * kN + w] : 0.f;
            int v2 = w0 + r, w2 = v0 + lane;
            tB[r][lane] = (v2 < kN && w2 < kN) ? av[(size_t)v2 * kN + w2] : 0.f;
        }
        __syncthreads();
        for (int r = wv; r < 64; r += 3) {
            int w = w0 + r;
            int v = v0 + lane;
            if (w < kN && v < kN) {
                size_t o = ((size_t)b * kWs + w) * kVs + v;
                float dlt = (v == w) ? 1.f : 0.f;
                {
                    float iv = 1.f / (1.f + P.rs[b * kN + v]);
                    float e = cBW * (tA[lane][r] + dlt) * iv + cGW * P.a0Tf[(size_t)w * kVs + v];
                    ushort_t hi, lo; split_bf(e, hi, lo);
                    P.E0h[o] = hi; P.E0l[o] = lo;
                }
                {
                    float iv = 1.f / (1.f + P.cs[b * kN + v]);
                    float e = cBW * (tB[r][lane] + dlt) * iv + cGW * P.a1Tf[(size_t)w * kVs + v];
                    ushort_t hi, lo; split_bf(e, hi, lo);
                    P.E1h[o] = hi; P.E1l[o] = lo;
                }
            }
        }
        __syncthreads();
    }
}

// ---------------------------------------------------------------------------
// gates wave-unit: z,r + tmp=[x, r*H]
__device__ __forceinline__ void d_gates(const KParams& P, int rb, int u, int lane) {
    const int pt = u % 164, hb = u / 164;
    const int p = pt * 64 + lane;
    const int h0 = hb * 4;
    const float* wz0 = P.rnw + (size_t)(rb + 0) * (kDIN * kHID) + h0;
    const float* wz1 = P.rnw + (size_t)(rb + 1) * (kDIN * kHID) + h0;
    const float* wr0 = P.rnw + (size_t)(rb + 2) * (kDIN * kHID) + h0;
    const float* wr1 = P.rnw + (size_t)(rb + 3) * (kDIN * kHID) + h0;
    float az[4] = {0.f, 0.f, 0.f, 0.f}, ar[4] = {0.f, 0.f, 0.f, 0.f};
    const float* segA[3] = {P.xH, P.hA1, P.hA2};
    const float* segB[3] = {P.xH, P.hB1, P.hB2};
#pragma unroll
    for (int seg = 0; seg < 3; ++seg) {
        const float* sA = segA[seg];
        const float* sB = segB[seg];
        const size_t wo = (size_t)seg * 66 * kHID;
#pragma unroll 2
        for (int kl = 0; kl < 66; ++kl) {
            float u0 = sA[(size_t)kl * kPc + p];
            float u1 = sB[(size_t)kl * kPc + p];
            float4 z0 = *(const float4*)(wz0 + wo + (size_t)kl * kHID);
            float4 z1 = *(const float4*)(wz1 + wo + (size_t)kl * kHID);
            float4 r0 = *(const float4*)(wr0 + wo + (size_t)kl * kHID);
            float4 r1 = *(const float4*)(wr1 + wo + (size_t)kl * kHID);
            az[0] = fmaf(u0, z0.x, az[0]); az[1] = fmaf(u0, z0.y, az[1]);
            az[2] = fmaf(u0, z0.z, az[2]); az[3] = fmaf(u0, z0.w, az[3]);
            az[0] = fmaf(u1, z1.x, az[0]); az[1] = fmaf(u1, z1.y, az[1]);
            az[2] = fmaf(u1, z1.z, az[2]); az[3] = fmaf(u1, z1.w, az[3]);
            ar[0] = fmaf(u0, r0.x, ar[0]); ar[1] = fmaf(u0, r0.y, ar[1]);
            ar[2] = fmaf(u0, r0.z, ar[2]); ar[3] = fmaf(u0, r0.w, ar[3]);
            ar[0] = fmaf(u1, r1.x, ar[0]); ar[1] = fmaf(u1, r1.y, ar[1]);
            ar[2] = fmaf(u1, r1.z, ar[2]); ar[3] = fmaf(u1, r1.w, ar[3]);
        }
    }
    const int b = p / kNP, n = p - b * kNP;
    const bool ok = (n < kN);
#pragma unroll
    for (int i = 0; i < 4; ++i) {
        float zz = sigm_f(az[i] + P.rnb[(rb + 0) * kHID + h0 + i] + P.rnb[(rb + 1) * kHID + h0 + i]);
        float rr = sigm_f(ar[i] + P.rnb[(rb + 2) * kHID + h0 + i] + P.rnb[(rb + 3) * kHID + h0 + i]);
        float tv = rr * P.xH[(size_t)(2 + h0 + i) * kPc + p];
        if (ok) {
            P.zbuf[(size_t)(h0 + i) * kPc + p] = zz;
            P.tmp[(size_t)(2 + h0 + i) * kPc + p] = tv;
        }
    }
    if (hb == 0 && ok) {
        P.tmp[p] = P.xH[p];
        P.tmp[kPc + p] = P.xH[kPc + p];
    }
}
__global__ __launch_bounds__(kT) void g_gates(KParams P, int rb) {
    const int lane = threadIdx.x & 63;
    const int gw = blockIdx.x * 3 + (threadIdx.x >> 6);
    const int nw = gridDim.x * 3;
    for (int u = gw; u < kGateU; u += nw) d_gates(P, rb, u, lane);
}

// ---------------------------------------------------------------------------
// final wave-unit: Cn + GRU update in place + next-step x rows
__device__ __forceinline__ void d_final(const KParams& P, int rb, int t, int nextmode,
                                        int u, int lane) {
    const int pt = u % 164, hb = u / 164;
    const int p = pt * 64 + lane;
    const int h0 = hb * 4;
    const float* wc0 = P.rnw + (size_t)(rb + 4) * (kDIN * kHID) + h0;
    const float* wc1 = P.rnw + (size_t)(rb + 5) * (kDIN * kHID) + h0;
    float ac[4] = {0.f, 0.f, 0.f, 0.f};
    const float* segA[3] = {P.tmp, P.hA1, P.hA2};
    const float* segB[3] = {P.tmp, P.hB1, P.hB2};
#pragma unroll
    for (int seg = 0; seg < 3; ++seg) {
        const float* sA = segA[seg];
        const float* sB = segB[seg];
        const size_t wo = (size_t)seg * 66 * kHID;
#pragma unroll 2
        for (int kl = 0; kl < 66; ++kl) {
            float u0 = sA[(size_t)kl * kPc + p];
            float u1 = sB[(size_t)kl * kPc + p];
            float4 w0 = *(const float4*)(wc0 + wo + (size_t)kl * kHID);
            float4 w1 = *(const float4*)(wc1 + wo + (size_t)kl * kHID);
            ac[0] = fmaf(u0, w0.x, ac[0]); ac[1] = fmaf(u0, w0.y, ac[1]);
            ac[2] = fmaf(u0, w0.z, ac[2]); ac[3] = fmaf(u0, w0.w, ac[3]);
            ac[0] = fmaf(u1, w1.x, ac[0]); ac[1] = fmaf(u1, w1.y, ac[1]);
            ac[2] = fmaf(u1, w1.z, ac[2]); ac[3] = fmaf(u1, w1.w, ac[3]);
        }
    }
    const int b = p / kNP, n = p - b * kNP;
    const bool ok = (n < kN);
#pragma unroll
    for (int i = 0; i < 4; ++i) {
        float cn = tanh_f(ac[i] + P.rnb[(rb + 4) * kHID + h0 + i] + P.rnb[(rb + 5) * kHID + h0 + i]);
        float zz = P.zbuf[(size_t)(h0 + i) * kPc + p];
        size_t hidx = (size_t)(2 + h0 + i) * kPc + p;
        float hv = P.xH[hidx];
        if (ok) P.xH[hidx] = zz * hv + (1.f - zz) * cn;
    }
    if (hb == 0 && ok && nextmode != 2) {
        float r0, r1;
        if (nextmode == 0) {
            r0 = P.hist[((b * kL + (t + 1)) * kN + n) * 2 + 0];
            r1 = P.hist[((b * kL + (t + 1)) * kN + n) * 2 + 1];
        } else {
            r0 = 0.f;
            r1 = P.fut[((b * kL + 0) * kN + n) * 2 + 1];
        }
        P.xH[p] = r0;
        P.xH[kPc + p] = r1;
    }
}
__global__ __launch_bounds__(kT) void g_final(KParams P, int rb, int t, int nextmode) {
    const int lane = threadIdx.x & 63;
    const int gw = blockIdx.x * 3 + (threadIdx.x >> 6);
    const int nw = gridDim.x * 3;
    for (int u = gw; u < kGateU; u += nw) d_final(P, rb, t, nextmode, u, lane);
}

// out wave-unit: readout + next dec x rows
__global__ __launch_bounds__(kT) void g_out(KParams P, int t) {
    const int lane = threadIdx.x & 63;
    const int gw = blockIdx.x * 3 + (threadIdx.x >> 6);
    const int nw = gridDim.x * 3;
    for (int u = gw; u < kOutU; u += nw) {
        const int p = u * 64 + lane;
        const int b = p / kNP, n = p - b * kNP;
        if (n >= kN) continue;
        float acc = P.fcb[0];
#pragma unroll
        for (int h = 0; h < kHID; ++h) acc = fmaf(P.xH[(size_t)(2 + h) * kPc + p], P.fcw[h], acc);
        P.out[(b * 12 + t) * kN + n] = acc;
        if (t + 1 < 12) {
            P.xH[p] = acc;
            P.xH[kPc + p] = P.fut[((b * kL + (t + 1)) * kN + n) * 2 + 1];
        }
    }
}

// ---------------------------------------------------------------------------
extern "C" void kernel_launch(void* const* d_in, const int* in_sizes, int n_in,
                              void* d_out, int out_size, void* d_ws, size_t ws_size,
                              hipStream_t stream) {
    KParams P;
    P.hist = (const float*)d_in[0];
    P.fut  = (const float*)d_in[1];
    P.adj0 = (const float*)d_in[2];
    P.adj1 = (const float*)d_in[3];
    P.emb1 = (const float*)d_in[4];
    P.emb2 = (const float*)d_in[5];
    P.hw1  = (const float*)d_in[6];
    P.hb1  = (const float*)d_in[7];
    P.hw2  = (const float*)d_in[8];
    P.hb2  = (const float*)d_in[9];
    P.hw3  = (const float*)d_in[10];
    P.hb3  = (const float*)d_in[11];
    P.rnw  = (const float*)d_in[12];
    P.rnb  = (const float*)d_in[13];
    P.fcw  = (const float*)d_in[14];
    P.fcb  = (const float*)d_in[15];
    P.out  = (float*)d_out;

    float* ws = (float*)d_ws;
    const size_t SEG = (size_t)66 * kPc;
    size_t off = 0;
    // h-buffers first (A-side channel-OOB reads stay inside ws)
    P.xH   = ws + off; off += SEG;
    P.hA1  = ws + off; off += SEG;
    P.hB1  = ws + off; off += SEG;
    P.hA2  = ws + off; off += SEG;
    P.hB2  = ws + off; off += SEG;
    P.tmp  = ws + off; off += SEG;
    P.nv1  = ws + off; off += (size_t)kND * kPc;
    P.nv2  = ws + off; off += (size_t)kND * kPc;
    P.zbuf = ws + off; off += (size_t)64 * kPc;
    P.s2g  = ws + off; off += (size_t)8 * kPc;
    P.e1T  = ws + off; off += kND * kN;
    P.e2T  = ws + off; off += kND * kN;
    P.rs   = ws + off; off += kB * kN;
    P.cs   = ws + off; off += kB * kN;
    P.adjv = ws + off; off += (size_t)kB * kNN2;
    P.a0Tf = ws + off; off += kETb;
    P.a1Tf = ws + off; off += kETb;
    // contiguous bf16 E block (zeroed as one range in init)
    P.E0h  = (ushort_t*)(ws + off); off += (size_t)kB * kETb / 2;
    P.E0l  = (ushort_t*)(ws + off); off += (size_t)kB * kETb / 2;
    P.E1h  = (ushort_t*)(ws + off); off += (size_t)kB * kETb / 2;
    P.E1l  = (ushort_t*)(ws + off); off += (size_t)kB * kETb / 2;
    P.a0h  = (ushort_t*)(ws + off); off += kETb / 2;
    P.a0l  = (ushort_t*)(ws + off); off += kETb / 2;
    P.a1h  = (ushort_t*)(ws + off); off += kETb / 2;
    P.a1l  = (ushort_t*)(ws + off); off += kETb / 2;

    const dim3 HG(6, 5, 64), HB(64);

    g_init<<<dim3(1024), dim3(kT), 0, stream>>>(P);
    for (int step = 0; step < 24; ++step) {
        const int dec = step >= 12;
        const int t = dec ? step - 12 : step;
        const int hy0 = dec ? 4 : 0;
        const int rb = dec ? 6 : 0;
        const int nextmode = dec ? 2 : (step == 11 ? 1 : 0);

        g_hopm<<<HG, HB, 0, stream>>>(P.a0h, P.a0l, P.a1h, P.a1l, 0,
                                      P.xH, P.xH, P.xH, P.hA1, P.hB1, cGW);
        g_hopm<<<HG, HB, 0, stream>>>(P.a0h, P.a0l, P.a1h, P.a1l, 0,
                                      P.hA1, P.hB1, P.xH, P.hA2, P.hB2, cGW);

        g_mlpA<<<dim3(kMlpAV), dim3(kT), 0, stream>>>(P, hy0);
        g_mlpB<<<dim3(kMlpBV), dim3(kT), 0, stream>>>(P, hy0);

        g_adj<<<dim3(1344), dim3(kT), 0, stream>>>(P);
        g_buildE<<<dim3(kBldEV), dim3(kT), 0, stream>>>(P);

        g_hopm<<<HG, HB, 0, stream>>>(P.E0h, P.E0l, P.E1h, P.E1l, kETb,
                                      P.xH, P.xH, P.xH, P.hA1, P.hB1, 1.f);
        g_hopm<<<HG, HB, 0, stream>>>(P.E0h, P.E0l, P.E1h, P.E1l, kETb,
                                      P.hA1, P.hB1, P.xH, P.hA2, P.hB2, 1.f);

        g_gates<<<dim3(875), dim3(kT), 0, stream>>>(P, rb);

        g_hopm<<<HG, HB, 0, stream>>>(P.E0h, P.E0l, P.E1h, P.E1l, kETb,
                                      P.tmp, P.tmp, P.tmp, P.hA1, P.hB1, 1.f);
        g_hopm<<<HG, HB, 0, stream>>>(P.E0h, P.E0l, P.E1h, P.E1l, kETb,
                                      P.hA1, P.hB1, P.tmp, P.hA2, P.hB2, 1.f);

        g_final<<<dim3(875), dim3(kT), 0, stream>>>(P, rb, t, nextmode);

        if (dec) g_out<<<dim3(55), dim3(kT), 0, stream>>>(P, t);
    }
    (void)in_sizes; (void)n_in; (void)out_size; (void)ws_size;
}

// Round 10
// 10577.144 us; speedup vs baseline: 1.6687x; 1.1144x over previous
//
#include <hip/hip_runtime.h>

typedef unsigned short ushort_t;

// ---- problem constants ----
constexpr int kB   = 32;
constexpr int kL   = 12;
constexpr int kN   = 325;
constexpr int kNP  = 328;          // padded node count
constexpr int kPc  = kB * kNP;     // 10496 column stride, channel-major
constexpr int kHID = 64;
constexpr int kDIN = 198;          // 3 * 66
constexpr int kND  = 40;
constexpr int kNN2 = kN * kN;
constexpr float cAW = 0.05f, cBW = 0.95f, cGW = 0.95f, cTA = 3.0f;

constexpr int kT = 192;            // threads for generic kernels (3 waves)
constexpr int kWs = 384;           // transposed-E w rows (6 strips x 64)
constexpr int kVs = 352;           // transposed-E v stride (11*32, padded)
constexpr int kETb = kWs * kVs;    // per-b elements = 135168

constexpr int kAdjU   = 4032;      // 6 jblk * 21 iblk * 32 b
constexpr int kBldEV  = 1152;      // 6 wblk * 6 vblk * 32 b
constexpr int kGateU  = 1312;      // 164 ptile * 8 hblk (8 outputs/wave)
constexpr int kOutU   = 164;

// init index-space regions
constexpr int kInit1 = 66 * kPc;                    // xH
constexpr int kInit2 = 2 * kND * kN;                // e1T/e2T
constexpr int kInit3 = 2 * kETb;                    // a0T/a1T hi/lo/f
constexpr int kInit4 = 4 * kB * kETb / 2;           // zero E block as uints
constexpr int kInit5 = 12 * kDIN * kHID;            // rnwC combos
constexpr int kInit6 = 8 * kDIN * 16;               // hw1C combos
constexpr int kInitT = kInit1 + kInit2 + kInit3 + kInit4 + kInit5 + kInit6;

using short8 = __attribute__((ext_vector_type(8))) short;
using f32x4  = __attribute__((ext_vector_type(4))) float;
union ABu { ushort_t u[8]; short8 v; };

__device__ __forceinline__ float sigm_f(float x) { return 1.f / (1.f + __expf(-x)); }
__device__ __forceinline__ float tanh_f(float x) { return 1.f - 2.f / (1.f + __expf(2.f * x)); }
__device__ __forceinline__ ushort_t f2b(float x) {   // fp32 -> bf16 RNE
    union { float f; unsigned u; } c; c.f = x;
    unsigned r = c.u + 0x7FFFu + ((c.u >> 16) & 1u);
    return (ushort_t)(r >> 16);
}
__device__ __forceinline__ float b2f(ushort_t h) {
    union { unsigned u; float f; } c; c.u = ((unsigned)h) << 16; return c.f;
}
__device__ __forceinline__ void split_bf(float x, ushort_t& hi, ushort_t& lo) {
    hi = f2b(x);
    lo = f2b(x - b2f(hi));
}

struct KParams {
    const float *hist, *fut, *adj0, *adj1, *emb1, *emb2;
    const float *hw1, *hb1, *hw2, *hb2, *hw3, *hb3, *rnw, *rnb, *fcw, *fcb;
    float* out;
    float *xH, *hA1, *hB1, *hA2, *hB2, *tmp;              // 6 SEG h-buffers
    float *nv1, *nv2, *zbuf, *e1T, *e2T, *rs, *cs, *adjv;
    float *a0Tf, *a1Tf;                                   // fp32 transposed adj [w][v]
    float *rnwC, *hw1C;                                   // combined weights
    ushort_t *E0h, *E0l, *E1h, *E1l;                      // bf16 hi/lo E^T [b][w][v]
    ushort_t *a0h, *a0l, *a1h, *a1l;                      // bf16 hi/lo adj^T [w][v]
};

// ---------------------------------------------------------------------------
__device__ __forceinline__ void d_init(const KParams& P, int i) {
    if (i < kInit1) {
        int c = i / kPc, p = i - c * kPc;
        int b = p / kNP, n = p - b * kNP;
        if (n < kN) {
            float v = (c < 2) ? P.hist[((b * kL) * kN + n) * 2 + c] : 0.f;
            P.xH[(size_t)c * kPc + p] = v;
        }
        return;
    }
    int j = i - kInit1;
    if (j < kND * kN) { int d = j / kN, n = j - d * kN; P.e1T[j] = P.emb1[n * kND + d]; return; }
    j -= kND * kN;
    if (j < kND * kN) { int d = j / kN, n = j - d * kN; P.e2T[j] = P.emb2[n * kND + d]; return; }
    j -= kND * kN;
    if (j < kInit3) {
        int m = j / kETb, idx = j - m * kETb;
        int w = idx / kVs, v = idx - w * kVs;
        const float* adj = m ? P.adj1 : P.adj0;
        float val = (w < kN && v < kN) ? adj[(size_t)v * kN + w] : 0.f;
        ushort_t hi, lo; split_bf(val, hi, lo);
        if (m) { P.a1h[idx] = hi; P.a1l[idx] = lo; P.a1Tf[idx] = val; }
        else   { P.a0h[idx] = hi; P.a0l[idx] = lo; P.a0Tf[idx] = val; }
        return;
    }
    j -= kInit3;
    if (j < kInit4) { ((unsigned*)P.E0h)[j] = 0; return; }   // E0h..E1l contiguous
    j -= kInit4;
    if (j < kInit5) {
        int m = j / (kDIN * kHID), rem = j - m * (kDIN * kHID);
        int k = rem / kHID, o = rem - k * kHID;
        const float* W = P.rnw + (size_t)m * (kDIN * kHID) + o;
        float v;
        if (k < 66)        v = W[(size_t)k * kHID] + cAW * (W[(size_t)(k + 66) * kHID] + W[(size_t)(k + 132) * kHID]);
        else if (k < 132)  v = W[(size_t)k * kHID] + cAW * W[(size_t)(k + 66) * kHID];
        else               v = W[(size_t)k * kHID];
        P.rnwC[j] = v;
        return;
    }
    j -= kInit5;
    if (j < kInit6) {
        int m = j / (kDIN * 16), rem = j - m * (kDIN * 16);
        int k = rem / 16, o = rem - k * 16;
        const float* W = P.hw1 + (size_t)m * (kDIN * 16) + o;
        float v;
        if (k < 66)        v = W[(size_t)k * 16] + cAW * (W[(size_t)(k + 66) * 16] + W[(size_t)(k + 132) * 16]);
        else if (k < 132)  v = cGW * (W[(size_t)k * 16] + cAW * W[(size_t)(k + 66) * 16]);
        else               v = cGW * cGW * W[(size_t)k * 16];
        P.hw1C[j] = v;
    }
}
__global__ __launch_bounds__(kT) void g_init(KParams P) {
    const int gtid = blockIdx.x * kT + threadIdx.x;
    const int nt = gridDim.x * kT;
    for (int i = gtid; i < kInitT; i += nt) d_init(P, i);
}

// ---------------------------------------------------------------------------
// Split-bf16 MFMA pure diffusion hop: out[c,b,w] = sum_v M[v,w]*h[c,b,v]
// M as transposed bf16 hi/lo MT[w][v] (v-stride kVs, pads zero).
// grid (6 wstrip, 64 = sel*32+b), block 320 (5 waves = 5 ctiles sharing L1 B).
__global__ __launch_bounds__(320) void g_hopm(
        const ushort_t* __restrict__ MaH, const ushort_t* __restrict__ MaL,
        const ushort_t* __restrict__ MbH, const ushort_t* __restrict__ MbL,
        int mstride,
        const float* __restrict__ hA, const float* __restrict__ hB,
        float* __restrict__ oA, float* __restrict__ oB) {
    const int lane = threadIdx.x & 63;
    const int ct = threadIdx.x >> 6;               // ctile 0..4
    const int quad = lane >> 4, ln15 = lane & 15;
    const int w0 = blockIdx.x * 64;
    const int zb = blockIdx.y;
    const int sel = zb >> 5, b = zb & 31;
    const ushort_t* EH = (sel ? MbH : MaH) + (size_t)b * mstride;
    const ushort_t* EL = (sel ? MbL : MaL) + (size_t)b * mstride;
    const float* hb = (sel ? hB : hA) + b * kNP;
    float* ob = (sel ? oB : oA) + b * kNP;
    const int ac = ct * 16 + ln15;                 // A channel for this lane
    const float* ap = hb + (size_t)ac * kPc + quad * 8;
    size_t brow[4];
#pragma unroll
    for (int nn = 0; nn < 4; ++nn)
        brow[nn] = (size_t)(w0 + nn * 16 + ln15) * kVs + quad * 8;

    f32x4 acc[4];
#pragma unroll
    for (int nn = 0; nn < 4; ++nn) acc[nn] = f32x4{0.f, 0.f, 0.f, 0.f};

    for (int ks = 0; ks < 11; ++ks) {
        const int v0 = ks * 32;
        float4 f0 = *(const float4*)(ap + v0);
        float4 f1 = *(const float4*)(ap + v0 + 4);
        float fs[8] = {f0.x, f0.y, f0.z, f0.w, f1.x, f1.y, f1.z, f1.w};
        ABu ah, al;
#pragma unroll
        for (int j = 0; j < 8; ++j) {
            ushort_t hi = f2b(fs[j]);
            ah.u[j] = hi;
            al.u[j] = f2b(fs[j] - b2f(hi));
        }
#pragma unroll
        for (int nn = 0; nn < 4; ++nn) {
            short8 bh = *(const short8*)(EH + brow[nn] + v0);
            short8 bl = *(const short8*)(EL + brow[nn] + v0);
            acc[nn] = __builtin_amdgcn_mfma_f32_16x16x32_bf16(ah.v, bh, acc[nn], 0, 0, 0);
            acc[nn] = __builtin_amdgcn_mfma_f32_16x16x32_bf16(al.v, bh, acc[nn], 0, 0, 0);
            acc[nn] = __builtin_amdgcn_mfma_f32_16x16x32_bf16(ah.v, bl, acc[nn], 0, 0, 0);
        }
    }
#pragma unroll
    for (int nn = 0; nn < 4; ++nn) {
        int w = w0 + nn * 16 + ln15;
        if (w < kN) {
#pragma unroll
            for (int r = 0; r < 4; ++r) {
                int c = ct * 16 + quad * 4 + r;
                if (c < 66) ob[(size_t)c * kPc + w] = acc[nn][r];
            }
        }
    }
}

// ---------------------------------------------------------------------------
// fused hyper MLP (uses combined hw1C on raw [x, v1, v2]):
// fc1 (K-split over 3 seg-waves) + fc2 + fc3 + nv = tanh(TA*emb*f)
// grid (164), block 768 (12 waves: wv = s*4+m); prologue zeroes rs/cs.
__global__ __launch_bounds__(768) void g_mlp(KParams P, int hy0) {
    {
        int zt = blockIdx.x * 768 + threadIdx.x;
        if (zt < kB * kN) P.rs[zt] = 0.f;
        else if (zt < 2 * kB * kN) P.cs[zt - kB * kN] = 0.f;
    }
    __shared__ float part[12][16][64];
    __shared__ float s2s[4][2][64];
    const int lane = threadIdx.x & 63;
    const int wv = threadIdx.x >> 6;
    const int p = blockIdx.x * 64 + lane;
    const int m = wv & 3, s = wv >> 2;
    const int ig = hy0 + m;
    const float* src = (s == 0) ? P.xH : (s == 1) ? ((m & 1) ? P.hB1 : P.hA1)
                                                  : ((m & 1) ? P.hB2 : P.hA2);
    const float* wp = P.hw1C + (size_t)ig * (kDIN * 16);
    float acc[16];
#pragma unroll
    for (int o = 0; o < 16; ++o) acc[o] = 0.f;
#pragma unroll 2
    for (int kl = 0; kl < 66; ++kl) {
        int kk = s * 66 + kl;
        float u = src[(size_t)kl * kPc + p];
        float4 wa = *(const float4*)(wp + kk * 16);
        float4 wb = *(const float4*)(wp + kk * 16 + 4);
        float4 wc = *(const float4*)(wp + kk * 16 + 8);
        float4 wd = *(const float4*)(wp + kk * 16 + 12);
        acc[0]  = fmaf(u, wa.x, acc[0]);  acc[1]  = fmaf(u, wa.y, acc[1]);
        acc[2]  = fmaf(u, wa.z, acc[2]);  acc[3]  = fmaf(u, wa.w, acc[3]);
        acc[4]  = fmaf(u, wb.x, acc[4]);  acc[5]  = fmaf(u, wb.y, acc[5]);
        acc[6]  = fmaf(u, wb.z, acc[6]);  acc[7]  = fmaf(u, wb.w, acc[7]);
        acc[8]  = fmaf(u, wc.x, acc[8]);  acc[9]  = fmaf(u, wc.y, acc[9]);
        acc[10] = fmaf(u, wc.z, acc[10]); acc[11] = fmaf(u, wc.w, acc[11]);
        acc[12] = fmaf(u, wd.x, acc[12]); acc[13] = fmaf(u, wd.y, acc[13]);
        acc[14] = fmaf(u, wd.z, acc[14]); acc[15] = fmaf(u, wd.w, acc[15]);
    }
#pragma unroll
    for (int o = 0; o < 16; ++o) part[wv][o][lane] = acc[o];
    __syncthreads();
    if (wv < 4) {
        int mm = wv, igm = hy0 + mm;
        float sv[16];
#pragma unroll
        for (int o = 0; o < 16; ++o)
            sv[o] = sigm_f(P.hb1[igm * 16 + o] + part[mm][o][lane] + part[4 + mm][o][lane] + part[8 + mm][o][lane]);
#pragma unroll
        for (int j = 0; j < 2; ++j) {
            float t = P.hb2[igm * 2 + j];
#pragma unroll
            for (int o = 0; o < 16; ++o) t = fmaf(sv[o], P.hw2[igm * 32 + o * 2 + j], t);
            s2s[mm][j][lane] = sigm_f(t);
        }
    }
    __syncthreads();
    int b = p / kNP, n = p - b * kNP;
    int nc = (n < kN) ? n : (kN - 1);
    bool ok = (n < kN);
    if (wv < 2) {
        int i0 = hy0 + wv * 2;
        float sa0 = s2s[wv * 2 + 0][0][lane], sa1 = s2s[wv * 2 + 0][1][lane];
        float sb0 = s2s[wv * 2 + 1][0][lane], sb1 = s2s[wv * 2 + 1][1][lane];
        const float* eT = wv ? P.e2T : P.e1T;
        float* nv = wv ? P.nv2 : P.nv1;
#pragma unroll 4
        for (int d = 0; d < kND; ++d) {
            float f = P.hb3[(i0 + 0) * kND + d] + P.hb3[(i0 + 1) * kND + d]
                    + sa0 * P.hw3[(i0 + 0) * 80 + d] + sa1 * P.hw3[(i0 + 0) * 80 + 40 + d]
                    + sb0 * P.hw3[(i0 + 1) * 80 + d] + sb1 * P.hw3[(i0 + 1) * 80 + 40 + d];
            float r = tanh_f(cTA * eT[d * kN + nc] * f);
            if (ok) nv[(size_t)d * kPc + p] = r;
        }
    }
}

// ---------------------------------------------------------------------------
// adj wave-unit: adjv[i][j] = relu(tanh(TA*(a_ij - a_ji))) + rs/cs atomics
__device__ __forceinline__ void d_adj(const KParams& P, int u, int lane) {
    const int jblk = u % 6;
    const int rem = u / 6;
    const int iblk = rem % 21;
    const int b = rem / 21;
    const int j = jblk * 64 + lane;
    const bool jok = (j < kN);
    const int jc = jok ? j : (kN - 1);
    const int i0 = iblk * 16;
    const float* p1 = P.nv1 + b * kNP;
    const float* p2 = P.nv2 + b * kNP;
    float aij[16], aji[16];
#pragma unroll
    for (int q = 0; q < 16; ++q) { aij[q] = 0.f; aji[q] = 0.f; }
#pragma unroll 2
    for (int d = 0; d < kND; ++d) {
        const float* r1 = p1 + (size_t)d * kPc;
        const float* r2 = p2 + (size_t)d * kPc;
        float x1j = r1[jc];
        float x2j = r2[jc];
        float4 v1a = *(const float4*)(r1 + i0);
        float4 v1b = *(const float4*)(r1 + i0 + 4);
        float4 v1c = *(const float4*)(r1 + i0 + 8);
        float4 v1d = *(const float4*)(r1 + i0 + 12);
        float4 v2a = *(const float4*)(r2 + i0);
        float4 v2b = *(const float4*)(r2 + i0 + 4);
        float4 v2c = *(const float4*)(r2 + i0 + 8);
        float4 v2d = *(const float4*)(r2 + i0 + 12);
        float w1v[16] = {v1a.x,v1a.y,v1a.z,v1a.w, v1b.x,v1b.y,v1b.z,v1b.w,
                         v1c.x,v1c.y,v1c.z,v1c.w, v1d.x,v1d.y,v1d.z,v1d.w};
        float w2v[16] = {v2a.x,v2a.y,v2a.z,v2a.w, v2b.x,v2b.y,v2b.z,v2b.w,
                         v2c.x,v2c.y,v2c.z,v2c.w, v2d.x,v2d.y,v2d.z,v2d.w};
#pragma unroll
        for (int q = 0; q < 16; ++q) {
            aij[q] = fmaf(w1v[q], x2j, aij[q]);
            aji[q] = fmaf(x1j, w2v[q], aji[q]);
        }
    }
    size_t base = (size_t)b * kNN2;
    float colsum = 0.f;
#pragma unroll
    for (int q = 0; q < 16; ++q) {
        int i = i0 + q;
        float tv = tanh_f(cTA * (aij[q] - aji[q]));
        float av = fmaxf(tv, 0.f);
        bool okk = (i < kN) && jok;
        if (okk) P.adjv[base + (size_t)i * kN + j] = av;
        float rv = okk ? av : 0.f;
        colsum += rv;
        float rsum = rv;
#pragma unroll
        for (int off = 32; off; off >>= 1) rsum += __shfl_down(rsum, off);
        if (lane == 0 && i < kN) atomicAdd(&P.rs[b * kN + i], rsum);
    }
    if (jok) atomicAdd(&P.cs[b * kN + j], colsum);
}
__global__ __launch_bounds__(kT) void g_adj(KParams P) {
    const int lane = threadIdx.x & 63;
    const int gw = blockIdx.x * 3 + (threadIdx.x >> 6);
    const int nw = gridDim.x * 3;
    for (int u = gw; u < kAdjU; u += nw) d_adj(P, u, lane);
}

// ---------------------------------------------------------------------------
// buildE: writes transposed bf16 hi/lo E0/E1: E^T[b][w][v], v-stride kVs.
__global__ __launch_bounds__(kT) void g_buildE(KParams P) {
    __shared__ float tA[64][65];
    __shared__ float tB[64][65];
    for (int vb = blockIdx.x; vb < kBldEV; vb += gridDim.x) {
        const int lane = threadIdx.x & 63;
        const int wv = threadIdx.x >> 6;
        const int w0 = (vb % 6) * 64;
        const int v0 = ((vb / 6) % 6) * 64;
        const int b = vb / 36;
        const float* av = P.adjv + (size_t)b * kNN2;
        for (int r = wv; r < 64; r += 3) {
            int v = v0 + r, w = w0 + lane;
            tA[r][lane] = (v < kN && w < kN) ? av[(size_t)v * kN + w] : 0.f;
            int v2 = w0 + r, w2 = v0 + lane;
            tB[r][lane] = (v2 < kN && w2 < kN) ? av[(size_t)v2 * kN + w2] : 0.f;
        }
        __syncthreads();
        for (int r = wv; r < 64; r += 3) {
            int w = w0 + r;
            int v = v0 + lane;
            if (w < kN && v < kN) {
                size_t o = ((size_t)b * kWs + w) * kVs + v;
                float dlt = (v == w) ? 1.f : 0.f;
                {
                    float iv = 1.f / (1.f + P.rs[b * kN + v]);
                    float e = cBW * (tA[lane][r] + dlt) * iv + cGW * P.a0Tf[(size_t)w * kVs + v];
                    ushort_t hi, lo; split_bf(e, hi, lo);
                    P.E0h[o] = hi; P.E0l[o] = lo;
                }
                {
                    float iv = 1.f / (1.f + P.cs[b * kN + v]);
                    float e = cBW * (tB[r][lane] + dlt) * iv + cGW * P.a1Tf[(size_t)w * kVs + v];
                    ushort_t hi, lo; split_bf(e, hi, lo);
                    P.E1h[o] = hi; P.E1l[o] = lo;
                }
            }
        }
        __syncthreads();
    }
}

// ---------------------------------------------------------------------------
// gates wave-unit (8 outputs): z,r + tmp=[x, r*H]; combined weights rnwC.
__device__ __forceinline__ void d_gates(const KParams& P, int rb, int u, int lane) {
    const int pt = u % 164, hb = u / 164;
    const int p = pt * 64 + lane;
    const int h0 = hb * 8;
    const float* wz0 = P.rnwC + (size_t)(rb + 0) * (kDIN * kHID) + h0;
    const float* wz1 = P.rnwC + (size_t)(rb + 1) * (kDIN * kHID) + h0;
    const float* wr0 = P.rnwC + (size_t)(rb + 2) * (kDIN * kHID) + h0;
    const float* wr1 = P.rnwC + (size_t)(rb + 3) * (kDIN * kHID) + h0;
    float az[8], ar[8];
#pragma unroll
    for (int i = 0; i < 8; ++i) { az[i] = 0.f; ar[i] = 0.f; }
    const float* segA[3] = {P.xH, P.hA1, P.hA2};
    const float* segB[3] = {P.xH, P.hB1, P.hB2};
#pragma unroll
    for (int seg = 0; seg < 3; ++seg) {
        const float* sA = segA[seg];
        const float* sB = segB[seg];
        const size_t wo = (size_t)seg * 66 * kHID;
#pragma unroll 2
        for (int kl = 0; kl < 66; ++kl) {
            float u0 = sA[(size_t)kl * kPc + p];
            float u1 = sB[(size_t)kl * kPc + p];
            const size_t ro = wo + (size_t)kl * kHID;
#pragma unroll
            for (int hq = 0; hq < 2; ++hq) {
                float4 z0 = *(const float4*)(wz0 + ro + hq * 4);
                float4 z1 = *(const float4*)(wz1 + ro + hq * 4);
                float4 r0 = *(const float4*)(wr0 + ro + hq * 4);
                float4 r1 = *(const float4*)(wr1 + ro + hq * 4);
                int q = hq * 4;
                az[q+0] = fmaf(u0, z0.x, az[q+0]); az[q+1] = fmaf(u0, z0.y, az[q+1]);
                az[q+2] = fmaf(u0, z0.z, az[q+2]); az[q+3] = fmaf(u0, z0.w, az[q+3]);
                az[q+0] = fmaf(u1, z1.x, az[q+0]); az[q+1] = fmaf(u1, z1.y, az[q+1]);
                az[q+2] = fmaf(u1, z1.z, az[q+2]); az[q+3] = fmaf(u1, z1.w, az[q+3]);
                ar[q+0] = fmaf(u0, r0.x, ar[q+0]); ar[q+1] = fmaf(u0, r0.y, ar[q+1]);
                ar[q+2] = fmaf(u0, r0.z, ar[q+2]); ar[q+3] = fmaf(u0, r0.w, ar[q+3]);
                ar[q+0] = fmaf(u1, r1.x, ar[q+0]); ar[q+1] = fmaf(u1, r1.y, ar[q+1]);
                ar[q+2] = fmaf(u1, r1.z, ar[q+2]); ar[q+3] = fmaf(u1, r1.w, ar[q+3]);
            }
        }
    }
    const int b = p / kNP, n = p - b * kNP;
    const bool ok = (n < kN);
#pragma unroll
    for (int i = 0; i < 8; ++i) {
        float zz = sigm_f(az[i] + P.rnb[(rb + 0) * kHID + h0 + i] + P.rnb[(rb + 1) * kHID + h0 + i]);
        float rr = sigm_f(ar[i] + P.rnb[(rb + 2) * kHID + h0 + i] + P.rnb[(rb + 3) * kHID + h0 + i]);
        float tv = rr * P.xH[(size_t)(2 + h0 + i) * kPc + p];
        if (ok) {
            P.zbuf[(size_t)(h0 + i) * kPc + p] = zz;
            P.tmp[(size_t)(2 + h0 + i) * kPc + p] = tv;
        }
    }
    if (hb == 0 && ok) {
        P.tmp[p] = P.xH[p];
        P.tmp[kPc + p] = P.xH[kPc + p];
    }
}
__global__ __launch_bounds__(kT) void g_gates(KParams P, int rb) {
    const int lane = threadIdx.x & 63;
    const int gw = blockIdx.x * 3 + (threadIdx.x >> 6);
    const int nw = gridDim.x * 3;
    for (int u = gw; u < kGateU; u += nw) d_gates(P, rb, u, lane);
}

// ---------------------------------------------------------------------------
// final wave-unit (8 outputs): Cn + GRU update + next-step x rows
__device__ __forceinline__ void d_final(const KParams& P, int rb, int t, int nextmode,
                                        int u, int lane) {
    const int pt = u % 164, hb = u / 164;
    const int p = pt * 64 + lane;
    const int h0 = hb * 8;
    const float* wc0 = P.rnwC + (size_t)(rb + 4) * (kDIN * kHID) + h0;
    const float* wc1 = P.rnwC + (size_t)(rb + 5) * (kDIN * kHID) + h0;
    float ac[8];
#pragma unroll
    for (int i = 0; i < 8; ++i) ac[i] = 0.f;
    const float* segA[3] = {P.tmp, P.hA1, P.hA2};
    const float* segB[3] = {P.tmp, P.hB1, P.hB2};
#pragma unroll
    for (int seg = 0; seg < 3; ++seg) {
        const float* sA = segA[seg];
        const float* sB = segB[seg];
        const size_t wo = (size_t)seg * 66 * kHID;
#pragma unroll 2
        for (int kl = 0; kl < 66; ++kl) {
            float u0 = sA[(size_t)kl * kPc + p];
            float u1 = sB[(size_t)kl * kPc + p];
            const size_t ro = wo + (size_t)kl * kHID;
#pragma unroll
            for (int hq = 0; hq < 2; ++hq) {
                float4 w0 = *(const float4*)(wc0 + ro + hq * 4);
                float4 w1 = *(const float4*)(wc1 + ro + hq * 4);
                int q = hq * 4;
                ac[q+0] = fmaf(u0, w0.x, ac[q+0]); ac[q+1] = fmaf(u0, w0.y, ac[q+1]);
                ac[q+2] = fmaf(u0, w0.z, ac[q+2]); ac[q+3] = fmaf(u0, w0.w, ac[q+3]);
                ac[q+0] = fmaf(u1, w1.x, ac[q+0]); ac[q+1] = fmaf(u1, w1.y, ac[q+1]);
                ac[q+2] = fmaf(u1, w1.z, ac[q+2]); ac[q+3] = fmaf(u1, w1.w, ac[q+3]);
            }
        }
    }
    const int b = p / kNP, n = p - b * kNP;
    const bool ok = (n < kN);
#pragma unroll
    for (int i = 0; i < 8; ++i) {
        float cn = tanh_f(ac[i] + P.rnb[(rb + 4) * kHID + h0 + i] + P.rnb[(rb + 5) * kHID + h0 + i]);
        float zz = P.zbuf[(size_t)(h0 + i) * kPc + p];
        size_t hidx = (size_t)(2 + h0 + i) * kPc + p;
        float hv = P.xH[hidx];
        if (ok) P.xH[hidx] = zz * hv + (1.f - zz) * cn;
    }
    if (hb == 0 && ok && nextmode != 2) {
        float r0, r1;
        if (nextmode == 0) {
            r0 = P.hist[((b * kL + (t + 1)) * kN + n) * 2 + 0];
            r1 = P.hist[((b * kL + (t + 1)) * kN + n) * 2 + 1];
        } else {
            r0 = 0.f;
            r1 = P.fut[((b * kL + 0) * kN + n) * 2 + 1];
        }
        P.xH[p] = r0;
        P.xH[kPc + p] = r1;
    }
}
__global__ __launch_bounds__(kT) void g_final(KParams P, int rb, int t, int nextmode) {
    const int lane = threadIdx.x & 63;
    const int gw = blockIdx.x * 3 + (threadIdx.x >> 6);
    const int nw = gridDim.x * 3;
    for (int u = gw; u < kGateU; u += nw) d_final(P, rb, t, nextmode, u, lane);
}

// out wave-unit: readout + next dec x rows
__global__ __launch_bounds__(kT) void g_out(KParams P, int t) {
    const int lane = threadIdx.x & 63;
    const int gw = blockIdx.x * 3 + (threadIdx.x >> 6);
    const int nw = gridDim.x * 3;
    for (int u = gw; u < kOutU; u += nw) {
        const int p = u * 64 + lane;
        const int b = p / kNP, n = p - b * kNP;
        if (n >= kN) continue;
        float acc = P.fcb[0];
#pragma unroll
        for (int h = 0; h < kHID; ++h) acc = fmaf(P.xH[(size_t)(2 + h) * kPc + p], P.fcw[h], acc);
        P.out[(b * 12 + t) * kN + n] = acc;
        if (t + 1 < 12) {
            P.xH[p] = acc;
            P.xH[kPc + p] = P.fut[((b * kL + (t + 1)) * kN + n) * 2 + 1];
        }
    }
}

// ---------------------------------------------------------------------------
extern "C" void kernel_launch(void* const* d_in, const int* in_sizes, int n_in,
                              void* d_out, int out_size, void* d_ws, size_t ws_size,
                              hipStream_t stream) {
    KParams P;
    P.hist = (const float*)d_in[0];
    P.fut  = (const float*)d_in[1];
    P.adj0 = (const float*)d_in[2];
    P.adj1 = (const float*)d_in[3];
    P.emb1 = (const float*)d_in[4];
    P.emb2 = (const float*)d_in[5];
    P.hw1  = (const float*)d_in[6];
    P.hb1  = (const float*)d_in[7];
    P.hw2  = (const float*)d_in[8];
    P.hb2  = (const float*)d_in[9];
    P.hw3  = (const float*)d_in[10];
    P.hb3  = (const float*)d_in[11];
    P.rnw  = (const float*)d_in[12];
    P.rnb  = (const float*)d_in[13];
    P.fcw  = (const float*)d_in[14];
    P.fcb  = (const float*)d_in[15];
    P.out  = (float*)d_out;

    float* ws = (float*)d_ws;
    const size_t SEG = (size_t)66 * kPc;
    size_t off = 0;
    P.xH   = ws + off; off += SEG;
    P.hA1  = ws + off; off += SEG;
    P.hB1  = ws + off; off += SEG;
    P.hA2  = ws + off; off += SEG;
    P.hB2  = ws + off; off += SEG;
    P.tmp  = ws + off; off += SEG;
    P.nv1  = ws + off; off += (size_t)kND * kPc;
    P.nv2  = ws + off; off += (size_t)kND * kPc;
    P.zbuf = ws + off; off += (size_t)64 * kPc;
    P.e1T  = ws + off; off += kND * kN;
    P.e2T  = ws + off; off += kND * kN;
    P.rs   = ws + off; off += kB * kN;
    P.cs   = ws + off; off += kB * kN;
    P.adjv = ws + off; off += (size_t)kB * kNN2;
    P.a0Tf = ws + off; off += kETb;
    P.a1Tf = ws + off; off += kETb;
    P.rnwC = ws + off; off += (size_t)12 * kDIN * kHID;
    P.hw1C = ws + off; off += (size_t)8 * kDIN * 16;
    P.E0h  = (ushort_t*)(ws + off); off += (size_t)kB * kETb / 2;
    P.E0l  = (ushort_t*)(ws + off); off += (size_t)kB * kETb / 2;
    P.E1h  = (ushort_t*)(ws + off); off += (size_t)kB * kETb / 2;
    P.E1l  = (ushort_t*)(ws + off); off += (size_t)kB * kETb / 2;
    P.a0h  = (ushort_t*)(ws + off); off += kETb / 2;
    P.a0l  = (ushort_t*)(ws + off); off += kETb / 2;
    P.a1h  = (ushort_t*)(ws + off); off += kETb / 2;
    P.a1l  = (ushort_t*)(ws + off); off += kETb / 2;

    const dim3 HG(6, 64), HB(320);

    g_init<<<dim3(1024), dim3(kT), 0, stream>>>(P);
    for (int step = 0; step < 24; ++step) {
        const int dec = step >= 12;
        const int t = dec ? step - 12 : step;
        const int hy0 = dec ? 4 : 0;
        const int rb = dec ? 6 : 0;
        const int nextmode = dec ? 2 : (step == 11 ? 1 : 0);

        g_hopm<<<HG, HB, 0, stream>>>(P.a0h, P.a0l, P.a1h, P.a1l, 0,
                                      P.xH, P.xH, P.hA1, P.hB1);
        g_hopm<<<HG, HB, 0, stream>>>(P.a0h, P.a0l, P.a1h, P.a1l, 0,
                                      P.hA1, P.hB1, P.hA2, P.hB2);

        g_mlp<<<dim3(kPc / 64), dim3(768), 0, stream>>>(P, hy0);

        g_adj<<<dim3(1344), dim3(kT), 0, stream>>>(P);
        g_buildE<<<dim3(kBldEV), dim3(kT), 0, stream>>>(P);

        g_hopm<<<HG, HB, 0, stream>>>(P.E0h, P.E0l, P.E1h, P.E1l, kETb,
                                      P.xH, P.xH, P.hA1, P.hB1);
        g_hopm<<<HG, HB, 0, stream>>>(P.E0h, P.E0l, P.E1h, P.E1l, kETb,
                                      P.hA1, P.hB1, P.hA2, P.hB2);

        g_gates<<<dim3(438), dim3(kT), 0, stream>>>(P, rb);

        g_hopm<<<HG, HB, 0, stream>>>(P.E0h, P.E0l, P.E1h, P.E1l, kETb,
                                      P.tmp, P.tmp, P.hA1, P.hB1);
        g_hopm<<<HG, HB, 0, stream>>>(P.E0h, P.E0l, P.E1h, P.E1l, kETb,
                                      P.hA1, P.hB1, P.hA2, P.hB2);

        g_final<<<dim3(438), dim3(kT), 0, stream>>>(P, rb, t, nextmode);

        if (dec) g_out<<<dim3(55), dim3(kT), 0, stream>>>(P, t);
    }
    (void)in_sizes; (void)n_in; (void)out_size; (void)ws_size;
}